// Round 7
// baseline (598.492 us; speedup 1.0000x reference)
//
#include <hip/hip_runtime.h>
#include <hip/hip_bf16.h>

// Problem constants (from reference)
#define SN 50000
#define EN 20000
#define KN 128
#define DN 64
#define BN 4096
#define NE 1000000
#define NLAYER 3

// Column-chunk bucketing: chunk = 4096 gather-table rows (fp8: 0.5MB)
#define CH_SHIFT 12
#define NCH0 5                        // side0 (ui): cols index kdiff, EN -> 5 chunks
#define NCH1 13                       // side1 (iu): cols index stat,  SN -> 13 chunks
// fine bucket = (2*row + tagbit)*nch + chunk   (tagbit 0 = pos, 1 = neg)
#define SIDE1_BASE2 (2 * SN * NCH0)            // 500000
#define NTOT2 (2 * (SN * NCH0 + EN * NCH1))    // 1020000 fine buckets

// Two-pass partition sort
#define BIN_SHIFT 11
#define NBIN2 ((NTOT2 + 2047) >> 11)  // 499 coarse bins (2048 fine buckets each)
#define T1 4096                       // edges per part1 tile
#define PG1 ((NE + T1 - 1) / T1)      // 245 tiles per adjacency
#define HB 256                        // hist blocks per adjacency

typedef float f32x4 __attribute__((ext_vector_type(4)));
typedef float f32x2 __attribute__((ext_vector_type(2)));
typedef short bf16x8 __attribute__((ext_vector_type(8)));

__device__ __forceinline__ float sigmoidf_(float v) { return 1.f / (1.f + __expf(-v)); }
__device__ __forceinline__ float bf_lo(unsigned u) { return __uint_as_float(u << 16); }
__device__ __forceinline__ float bf_hi(unsigned u) { return __uint_as_float(u & 0xffff0000u); }
__device__ __forceinline__ float bf_one(unsigned short s) { return __uint_as_float((unsigned)s << 16); }
__device__ __forceinline__ unsigned packbf2(float a, float b) {
    __hip_bfloat16 ha = __float2bfloat16(a), hb = __float2bfloat16(b);
    unsigned short ua = *(unsigned short*)&ha, ub = *(unsigned short*)&hb;
    return (unsigned)ua | ((unsigned)ub << 16);
}
__device__ __forceinline__ unsigned short packbf1(float a) {
    __hip_bfloat16 ha = __float2bfloat16(a);
    return *(unsigned short*)&ha;
}
// fp8(e4m3) of a bf16 value — matches the old bf2fp8 two-step numerics
__device__ __forceinline__ unsigned char fp8_of_bf16(unsigned short h) {
    float f = bf_one(h);
    int pk = __builtin_amdgcn_cvt_pk_fp8_f32(f, f, 0, false);
    return (unsigned char)(pk & 0xff);
}

struct CsrB {
    const int* rows[4]; const int* cols[4]; const float* vals[4];
};

__device__ __forceinline__ int bucket_idx(int a, int r, int cc) {
    int side = a >> 1;
    int nch = side ? NCH1 : NCH0;
    int base = side ? SIDE1_BASE2 : 0;
    int tb = a & 1;                    // a=0,2 pos (first); a=1,3 neg (second)
    return base + (2 * r + tb) * nch + (cc >> CH_SHIFT);
}

// ---------------------------------------------------------------------------
// MERGED: coarse histogram (blocks 0..4*HB-1) + projection MFMA GEMM
// (remaining blocks). The two are independent (both only need f2bf3z's
// outputs: zeroed coarseCnt and the bf16 Kb table), both 256-thread.
// Merging removes one dispatch slot and overlaps hist's atomic-heavy
// blocks with proj's MFMA blocks on the same grid.
// ---------------------------------------------------------------------------
template <int KK>
__global__ __launch_bounds__(256) void hist_proj(
    CsrB c, int* __restrict__ cnt,
    const float* __restrict__ XS, const float* __restrict__ XE,
    const unsigned short* __restrict__ W,
    unsigned short* __restrict__ outS, unsigned char* __restrict__ f8S,
    unsigned short* __restrict__ outE, unsigned char* __restrict__ f8E,
    int nbS) {
    constexpr int PITCH = KK + 8;
    __shared__ int h[512];
    __shared__ unsigned short Wl[128 * PITCH];
    const int t = threadIdx.x;

    if ((int)blockIdx.x < 4 * HB) {
        // ---------------- histogram part ----------------
        h[t] = 0; h[t + 256] = 0;
        __syncthreads();
        const int a = blockIdx.x >> 8;
        const int tile = blockIdx.x & 255;
        const int per = (NE + HB - 1) / HB;
        const int beg = tile * per, end = min(beg + per, NE);
        for (int i = beg + t; i < end; i += 256)
            atomicAdd(&h[bucket_idx(a, c.rows[a][i], c.cols[a][i]) >> BIN_SHIFT], 1);
        __syncthreads();
        if (h[t]) atomicAdd(&cnt[t], h[t]);
        if (h[t + 256]) atomicAdd(&cnt[t + 256], h[t + 256]);
        return;
    }
    // ---------------- projection part ----------------
    const int bid = (int)blockIdx.x - 4 * HB;
    for (int idx = t * 8; idx < 128 * KK; idx += 2048) {
        int r = idx / KK, k = idx - r * KK;
        *(uint4*)(&Wl[r * PITCH + k]) = *(const uint4*)(&W[idx]);
    }
    __syncthreads();
    const bool sideE = bid >= nbS;
    const float* X = sideE ? XE : XS;
    unsigned short* out = sideE ? outE : outS;
    unsigned char* f8 = sideE ? f8E : f8S;
    const int M = sideE ? EN : SN;
    const int lane = t & 63;
    const int nm = lane & 15;
    const int quad = lane >> 4;
    const int row0 = (bid - (sideE ? nbS : 0)) * 64 + (t >> 6) * 16;
    if (row0 >= M) return;

    f32x4 acc[8];
#pragma unroll
    for (int nt = 0; nt < 8; ++nt) acc[nt] = (f32x4){0.f, 0.f, 0.f, 0.f};

    const float* xrow = X + (size_t)(row0 + nm) * KK + quad * 8;
#pragma unroll
    for (int ks = 0; ks < KK / 32; ++ks) {
        float4 f0 = *(const float4*)(xrow + ks * 32);
        float4 f1 = *(const float4*)(xrow + ks * 32 + 4);
        unsigned q[4] = {packbf2(f0.x, f0.y), packbf2(f0.z, f0.w),
                         packbf2(f1.x, f1.y), packbf2(f1.z, f1.w)};
        bf16x8 a = *(bf16x8*)q;
#pragma unroll
        for (int nt = 0; nt < 8; ++nt) {
            bf16x8 b = *(const bf16x8*)(&Wl[(nt * 16 + nm) * PITCH + ks * 32 + quad * 8]);
            acc[nt] = __builtin_amdgcn_mfma_f32_16x16x32_bf16(a, b, acc[nt], 0, 0, 0);
        }
    }
    const size_t obase = (size_t)(row0 + quad * 4) * 128 + nm;
    unsigned short* orow = out + obase;
    unsigned char* frow = f8 + obase;
#pragma unroll
    for (int r = 0; r < 4; ++r)
#pragma unroll
        for (int nt = 0; nt < 8; ++nt) {
            unsigned short hh = packbf1(acc[nt][r]);
            orow[(size_t)r * 128 + nt * 16] = hh;
            frow[(size_t)r * 128 + nt * 16] = fp8_of_bf16(hh);
        }
}

// 1-block exclusive scan of coarse counts -> base[NBIN2+1] and tails[NBIN2]
__global__ __launch_bounds__(512) void scan_coarse(const int* __restrict__ cnt,
                                                   int* __restrict__ base,
                                                   int* __restrict__ tails) {
    __shared__ int sh[512];
    const int t = threadIdx.x;
    const int v = (t < NBIN2) ? cnt[t] : 0;
    sh[t] = v;
    __syncthreads();
    for (int o = 1; o < 512; o <<= 1) {
        int x = sh[t]; int u = (t >= o) ? sh[t - o] : 0;
        __syncthreads(); sh[t] = x + u; __syncthreads();
    }
    if (t < NBIN2) {
        const int ex = sh[t] - v;
        base[t] = ex;
        tails[t] = ex;
    }
    if (t == 511) base[NBIN2] = sh[511];
}

// ---------------------------------------------------------------------------
// part1: multisplit edges into coarse-bin segments with coalesced writes.
// Record int2: .x = col(0..15) | fine_bucket_low11(17..27), .y = f32 val (plain)
// ---------------------------------------------------------------------------
__global__ __launch_bounds__(512) void part1(CsrB c, int* __restrict__ tails,
                                             int2* __restrict__ stg) {
    __shared__ int2 srec[T1];
    __shared__ unsigned short sbin[T1];
    __shared__ int h[512], offs[512], gbase[512], sc[512];
    const int t = threadIdx.x;
    const int a = blockIdx.x / PG1;
    const int tile = blockIdx.x - a * PG1;
    const int beg = tile * T1;
    const int cnt = min(T1, NE - beg);
    h[t] = 0;
    __syncthreads();

    int2 rec[8]; int rbin[8]; int rrank[8];
#pragma unroll
    for (int k = 0; k < 8; ++k) {
        int o = t + k * 512;
        if (o < cnt) {
            int i = beg + o;
            int cc = c.cols[a][i];
            int B = bucket_idx(a, c.rows[a][i], cc);
            int bin = B >> BIN_SHIFT;
            rec[k] = make_int2(cc | ((B & 2047) << 17), __float_as_int(c.vals[a][i]));
            rbin[k] = bin;
            rrank[k] = atomicAdd(&h[bin], 1);
        } else {
            rbin[k] = -1;
        }
    }
    __syncthreads();
    sc[t] = h[t];
    __syncthreads();
    for (int o = 1; o < 512; o <<= 1) {
        int x = sc[t]; int u = (t >= o) ? sc[t - o] : 0;
        __syncthreads(); sc[t] = x + u; __syncthreads();
    }
    offs[t] = sc[t] - h[t];
    if (h[t] > 0) gbase[t] = atomicAdd(&tails[t], h[t]);
    __syncthreads();
#pragma unroll
    for (int k = 0; k < 8; ++k) {
        if (rbin[k] >= 0) {
            int pos = offs[rbin[k]] + rrank[k];
            srec[pos] = rec[k];
            sbin[pos] = (unsigned short)rbin[k];
        }
    }
    __syncthreads();
    for (int idx = t; idx < cnt; idx += 512) {
        int b = sbin[idx];
        stg[gbase[b] + (idx - offs[b])] = srec[idx];
    }
}

// ---------------------------------------------------------------------------
// part2: one block per coarse bin. Builds fine histogram+prefix in LDS
// (producing rp_all), then scatters into the bin's own ~128KB window.
// cv record: .x = bare column, .y = f32 value
// ---------------------------------------------------------------------------
__global__ __launch_bounds__(512) void part2(const int* __restrict__ coarseBase,
                                             const int2* __restrict__ stg,
                                             int* __restrict__ rp,
                                             int2* __restrict__ cv) {
    __shared__ int cnt2[2048];
    __shared__ int tsum[512];
    const int b = blockIdx.x;
    const int t = threadIdx.x;
    const int fineBase = b << BIN_SHIFT;
    const int nf = min(2048, NTOT2 - fineBase);
    const int segBeg = coarseBase[b];
    const int segEnd = coarseBase[b + 1];
    for (int i = t; i < 2048; i += 512) cnt2[i] = 0;
    __syncthreads();
    for (int e = segBeg + t; e < segEnd; e += 512)
        atomicAdd(&cnt2[((unsigned)stg[e].x) >> 17], 1);
    __syncthreads();
    const int i4 = t * 4;
    int v0 = cnt2[i4], v1 = cnt2[i4 + 1], v2 = cnt2[i4 + 2], v3 = cnt2[i4 + 3];
    tsum[t] = v0 + v1 + v2 + v3;
    __syncthreads();
    for (int o = 1; o < 512; o <<= 1) {
        int x = tsum[t]; int u = (t >= o) ? tsum[t - o] : 0;
        __syncthreads(); tsum[t] = x + u; __syncthreads();
    }
    const int pre = (t == 0) ? 0 : tsum[t - 1];
    const int p0 = pre, p1 = pre + v0, p2 = p1 + v1, p3 = p2 + v2;
    cnt2[i4] = p0; cnt2[i4 + 1] = p1; cnt2[i4 + 2] = p2; cnt2[i4 + 3] = p3;
    if (i4 + 0 < nf) rp[fineBase + i4 + 0] = segBeg + p0;
    if (i4 + 1 < nf) rp[fineBase + i4 + 1] = segBeg + p1;
    if (i4 + 2 < nf) rp[fineBase + i4 + 2] = segBeg + p2;
    if (i4 + 3 < nf) rp[fineBase + i4 + 3] = segBeg + p3;
    if (b == NBIN2 - 1 && t == 511) rp[NTOT2] = segEnd;
    __syncthreads();
    for (int e = segBeg + t; e < segEnd; e += 512) {
        int2 r = stg[e];
        int pos = segBeg + atomicAdd(&cnt2[((unsigned)r.x) >> 17], 1);
        cv[pos] = make_int2(r.x & 0xFFFF, r.y);
    }
}

// ---------------------------------------------------------------------------
// fp32 -> bf16 conversion, all three weight tables in ONE dispatch.
// Also zeroes the coarse-histogram counters (stream-ordered before hist).
// ---------------------------------------------------------------------------
__global__ __launch_bounds__(256) void f2bf3z(
    const float* __restrict__ s0, unsigned short* __restrict__ d0, int n0,
    const float* __restrict__ s1, unsigned short* __restrict__ d1, int n1,
    const float* __restrict__ s2, unsigned short* __restrict__ d2, int n2,
    int* __restrict__ coarseCnt) {
    int j = blockIdx.x * 256 + threadIdx.x;
    if (j < 512) coarseCnt[j] = 0;
    const float* s; unsigned short* d;
    if (j < n0) { s = s0; d = d0; }
    else {
        j -= n0;
        if (j < n1) { s = s1; d = d1; }
        else {
            j -= n1;
            if (j >= n2) return;
            s = s2; d = d2;
        }
    }
    float2 f = ((const float2*)s)[j];
    ((unsigned*)d)[j] = packbf2(f.x, f.y);
}

// ---------------------------------------------------------------------------
// Fused dual-weight MFMA GEMM, BOTH sides in one dispatch (in-place safe):
//   out = (agg1 + d1.*y)@W1^T + (agg0 + d0.*y)@W0^T + (b1+b0)
// 512 threads / 128 rows per block. Full mode also writes the fp8 shadow
// inline. LIST mode (last layer): block processes 128 *list entries*;
// aggregation buffers compact [BN,128]; y,d gathered through ids; compact
// output (race-free under duplicate ids, bitwise-identical math).
// ---------------------------------------------------------------------------
template <bool LIST>
__global__ __launch_bounds__(512) void gemm2_mfma(
    const unsigned short* __restrict__ agg1S, const unsigned short* __restrict__ agg0S,
    const unsigned short* __restrict__ yS,
    const float* __restrict__ d1S, const float* __restrict__ d0S,
    unsigned short* __restrict__ outS, unsigned char* __restrict__ f8S,
    const unsigned short* __restrict__ agg1E, const unsigned short* __restrict__ agg0E,
    const unsigned short* __restrict__ yE,
    const float* __restrict__ d1E, const float* __restrict__ d0E,
    unsigned short* __restrict__ outE, unsigned char* __restrict__ f8E,
    const unsigned short* __restrict__ W1, const unsigned short* __restrict__ W0,
    const float* __restrict__ b1, const float* __restrict__ b0,
    const int* __restrict__ idsS, const int* __restrict__ idsE, int nblkS) {
    constexpr int PITCH = 136;
    __shared__ unsigned short Wl[2 * 128 * PITCH];
    const int t = threadIdx.x;
    for (int idx = t * 8; idx < 128 * 128; idx += 4096) {
        int r = idx >> 7, k = idx & 127;
        *(uint4*)(&Wl[r * PITCH + k]) = *(const uint4*)(&W1[idx]);
        *(uint4*)(&Wl[128 * PITCH + r * PITCH + k]) = *(const uint4*)(&W0[idx]);
    }
    __syncthreads();
    const bool sideE = (int)blockIdx.x >= nblkS;
    const unsigned short* agg1 = sideE ? agg1E : agg1S;
    const unsigned short* agg0 = sideE ? agg0E : agg0S;
    const unsigned short* y    = sideE ? yE : yS;
    const float* d1 = sideE ? d1E : d1S;
    const float* d0 = sideE ? d0E : d0S;
    unsigned short* out = sideE ? outE : outS;
    unsigned char* f8 = sideE ? f8E : f8S;
    const int M = LIST ? BN : (sideE ? EN : SN);
    const int lane = t & 63;
    const int nm = lane & 15;
    const int quad = lane >> 4;
    const int row0 = ((int)blockIdx.x - (sideE ? nblkS : 0)) * 128 + (t >> 6) * 16;
    if (row0 >= M) return;

    const int lrow = row0 + nm;                  // list index (LIST) or row
    int grow = lrow;                             // real row for y / d gathers
    if (LIST) grow = (sideE ? idsE : idsS)[lrow];

    const float d1v = d1[grow];
    const float d0v = d0[grow];

    f32x4 acc[8];
#pragma unroll
    for (int nt = 0; nt < 8; ++nt) acc[nt] = (f32x4){0.f, 0.f, 0.f, 0.f};

    const size_t rbA = (size_t)lrow * 128 + quad * 8;   // aggs: compact in LIST
    const size_t rbY = (size_t)grow * 128 + quad * 8;   // y: gathered in LIST
#pragma unroll
    for (int ks = 0; ks < 4; ++ks) {
        uint4 ua1 = *(const uint4*)(agg1 + rbA + ks * 32);
        uint4 ua0 = *(const uint4*)(agg0 + rbA + ks * 32);
        uint4 uy  = *(const uint4*)(y    + rbY + ks * 32);
        uint4 p1, p0;
        {
            unsigned* a1 = (unsigned*)&ua1; unsigned* a0 = (unsigned*)&ua0;
            unsigned* yy = (unsigned*)&uy;
            unsigned* q1 = (unsigned*)&p1; unsigned* q0 = (unsigned*)&p0;
#pragma unroll
            for (int w = 0; w < 4; ++w) {
                float ylo = bf_lo(yy[w]), yhi = bf_hi(yy[w]);
                q1[w] = packbf2(bf_lo(a1[w]) + d1v * ylo, bf_hi(a1[w]) + d1v * yhi);
                q0[w] = packbf2(bf_lo(a0[w]) + d0v * ylo, bf_hi(a0[w]) + d0v * yhi);
            }
        }
        bf16x8 af1 = *(bf16x8*)&p1;
        bf16x8 af0 = *(bf16x8*)&p0;
#pragma unroll
        for (int nt = 0; nt < 8; ++nt) {
            bf16x8 bw1 = *(const bf16x8*)(&Wl[(nt * 16 + nm) * PITCH + ks * 32 + quad * 8]);
            acc[nt] = __builtin_amdgcn_mfma_f32_16x16x32_bf16(af1, bw1, acc[nt], 0, 0, 0);
            bf16x8 bw0 = *(const bf16x8*)(&Wl[128 * PITCH + (nt * 16 + nm) * PITCH + ks * 32 + quad * 8]);
            acc[nt] = __builtin_amdgcn_mfma_f32_16x16x32_bf16(af0, bw0, acc[nt], 0, 0, 0);
        }
    }
    const size_t obase = (size_t)(row0 + quad * 4) * 128 + nm;
    unsigned short* orow = out + obase;
    unsigned char* frow = f8 + obase;
#pragma unroll
    for (int nt = 0; nt < 8; ++nt) {
        float bb = b1[nt * 16 + nm] + b0[nt * 16 + nm];
#pragma unroll
        for (int r = 0; r < 4; ++r) {
            unsigned short h = packbf1(acc[nt][r] + bb);
            orow[(size_t)r * 128 + nt * 16] = h;
            if (!LIST) frow[(size_t)r * 128 + nt * 16] = fp8_of_bf16(h);
        }
    }
}

// ---------------------------------------------------------------------------
// Quad-SPMM (round-1/3 form — empirical floor of all structural variants
// tried in rounds 2/4/5): 4 edges per wave instruction. Quarter-wave q
// handles edge e+q; lane c (0..15) covers cols 8c..8c+7 via one uint2 fp8
// gather + 4 cvt_pk_f32_fp8 + 4 packed-f32 FMAs. Tag phases serial (keeps
// one gather-table window live per wave; mixing thrashed per-XCD L2).
// Cross-quarter reduce via shfl_xor(16|32); quarter 0 writes the pos row,
// quarter 1 the neg row (16 lanes x 16B coalesced).
// LIST mode (last layer): only 2*BN waves; wave i handles row ids[i] and
// writes compact output row i (race-free under duplicate ids).
// ---------------------------------------------------------------------------
template <bool LIST>
__global__ __launch_bounds__(256) void spmm_all(
    const int* __restrict__ rp, const long long* __restrict__ cv,
    const unsigned char* __restrict__ kd8, const unsigned char* __restrict__ st8,
    unsigned short* __restrict__ as1, unsigned short* __restrict__ as0,
    unsigned short* __restrict__ ae1, unsigned short* __restrict__ ae0,
    const int* __restrict__ idsS, const int* __restrict__ idsE) {
    const int wave = (blockIdx.x * 256 + threadIdx.x) >> 6;
    const int lane = threadIdx.x & 63;
    const int NW = LIST ? 2 * BN : SN + EN;
    if (wave >= NW) return;
    const bool sideE = LIST ? (wave >= BN) : (wave >= SN);
    const int li = sideE ? (wave - (LIST ? BN : SN)) : wave;
    const int r = LIST ? (sideE ? idsE[li] : idsS[li]) : li;
    const int nch = sideE ? NCH1 : NCH0;
    const int* rpb = rp + (sideE ? SIDE1_BASE2 : 0);
    const int q = lane >> 4;           // quarter 0..3 -> edge e+q
    const int c = lane & 15;           // col group: cols 8c..8c+7
    const unsigned char* g8 = (sideE ? st8 : kd8) + c * 8;

    const int rbase = 2 * r * nch;
    const int e0 = rpb[rbase];
    const int em = rpb[rbase + nch];
    const int ee = rpb[rbase + 2 * nch];

    f32x2 accP[4], accN[4];
#pragma unroll
    for (int j = 0; j < 4; ++j) { accP[j] = (f32x2){0.f, 0.f}; accN[j] = (f32x2){0.f, 0.f}; }

#define QUAD(E, ACC)                                                        \
    {                                                                       \
        int col = (int)((E) & 0xFFFF);                                      \
        float v = __int_as_float((int)((E) >> 32));                         \
        f32x2 vv = {v, v};                                                  \
        uint2 u = *(const uint2*)(g8 + (col << 7));                         \
        ACC[0] += vv * __builtin_amdgcn_cvt_pk_f32_fp8((int)u.x, false);    \
        ACC[1] += vv * __builtin_amdgcn_cvt_pk_f32_fp8((int)u.x, true);     \
        ACC[2] += vv * __builtin_amdgcn_cvt_pk_f32_fp8((int)u.y, false);    \
        ACC[3] += vv * __builtin_amdgcn_cvt_pk_f32_fp8((int)u.y, true);     \
    }

    // phase 1: pos edges [e0, em)
    {
        int e = e0;
        for (; e + 16 <= em; e += 16) {
            long long E0 = cv[e + q];
            long long E1 = cv[e + 4 + q];
            long long E2 = cv[e + 8 + q];
            long long E3 = cv[e + 12 + q];
            QUAD(E0, accP) QUAD(E1, accP) QUAD(E2, accP) QUAD(E3, accP)
        }
        for (; e + 4 <= em; e += 4) {
            long long E0 = cv[e + q];
            QUAD(E0, accP)
        }
        if (e < em) {
            int idx = min(e + q, em - 1);
            long long E0 = cv[idx];
            if (e + q >= em) E0 &= 0xFFFFLL;   // keep col, zero value
            QUAD(E0, accP)
        }
    }
    // phase 2: neg edges [em, ee)
    {
        int e = em;
        for (; e + 16 <= ee; e += 16) {
            long long E0 = cv[e + q];
            long long E1 = cv[e + 4 + q];
            long long E2 = cv[e + 8 + q];
            long long E3 = cv[e + 12 + q];
            QUAD(E0, accN) QUAD(E1, accN) QUAD(E2, accN) QUAD(E3, accN)
        }
        for (; e + 4 <= ee; e += 4) {
            long long E0 = cv[e + q];
            QUAD(E0, accN)
        }
        if (e < ee) {
            int idx = min(e + q, ee - 1);
            long long E0 = cv[idx];
            if (e + q >= ee) E0 &= 0xFFFFLL;
            QUAD(E0, accN)
        }
    }
#undef QUAD

    // reduce over quarters (xor 16, then 32)
#pragma unroll
    for (int j = 0; j < 4; ++j) {
        accP[j].x += __shfl_xor(accP[j].x, 16);
        accP[j].y += __shfl_xor(accP[j].y, 16);
        accN[j].x += __shfl_xor(accN[j].x, 16);
        accN[j].y += __shfl_xor(accN[j].y, 16);
        accP[j].x += __shfl_xor(accP[j].x, 32);
        accP[j].y += __shfl_xor(accP[j].y, 32);
        accN[j].x += __shfl_xor(accN[j].x, 32);
        accN[j].y += __shfl_xor(accN[j].y, 32);
    }
    unsigned short* o1 = sideE ? ae1 : as1;
    unsigned short* o0 = sideE ? ae0 : as0;
    const int oi = LIST ? li : r;      // compact slot in LIST mode
    const int base = (oi << 7) + c * 8;
    if (q == 0) {
        uint4 w;
        w.x = packbf2(accP[0].x, accP[0].y);
        w.y = packbf2(accP[1].x, accP[1].y);
        w.z = packbf2(accP[2].x, accP[2].y);
        w.w = packbf2(accP[3].x, accP[3].y);
        *(uint4*)&o1[base] = w;
    } else if (q == 1) {
        uint4 w;
        w.x = packbf2(accN[0].x, accN[0].y);
        w.y = packbf2(accN[1].x, accN[1].y);
        w.z = packbf2(accN[2].x, accN[2].y);
        w.w = packbf2(accN[3].x, accN[3].y);
        *(uint4*)&o0[base] = w;
    }
}

// ---------------------------------------------------------------------------
// ENTIRE head in one kernel: each block owns 32 batch rows end-to-end.
//   x  = disc*(sig(statB+b)-sig(kdB))*kn_emb          (head1, in LDS)
//   h1 = sig(x @ |pn1_w|^T + pn1_b)                    (two 128-col passes)
//   h2 = sig(h1 @ |pn2_w|^T + pn2_b)
//   out= sig(h2 . |pn3_w| + pn3_b)
// Accumulation order identical to the previous pn1_fused/pn23_fused pair
// (ascending k in 32-wide tiles throughout) -> bitwise-identical results.
// ---------------------------------------------------------------------------
__global__ __launch_bounds__(256) void pn_head(
    const int* __restrict__ stu_id, const int* __restrict__ exer_id,
    const float* __restrict__ kn_emb, const unsigned short* __restrict__ statB,
    const unsigned short* __restrict__ kdB, const float* __restrict__ stu_bias,
    const float* __restrict__ e_disc,
    const float* __restrict__ pn1_w, const float* __restrict__ pn1_b,
    const float* __restrict__ pn2_w, const float* __restrict__ pn2_b,
    const float* __restrict__ pn3_w, const float* __restrict__ pn3_b,
    float* __restrict__ out) {
    constexpr int ROWS = 32;
    __shared__ float Xl[ROWS][128 + 1];     // x
    __shared__ float H1[ROWS][256 + 1];     // h1
    __shared__ float BT[32][128 + 1];       // staged |W| k-tile
    __shared__ float Sv[ROWS][128 + 1];     // h2
    __shared__ float wl[128];
    __shared__ float sdisc[ROWS], sbias[ROWS];
    const int t = threadIdx.x;
    const int row0 = blockIdx.x * ROWS;
    if (t < ROWS) {
        sdisc[t] = sigmoidf_(e_disc[exer_id[row0 + t]]);
        sbias[t] = stu_bias[stu_id[row0 + t]];
    }
    if (t < 128) wl[t] = fabsf(pn3_w[t]);
    __syncthreads();
    for (int idx = t; idx < ROWS * 128; idx += 256) {
        const int r = idx >> 7, k = idx & 127;
        const int gr = row0 + r;
        const float sb = sigmoidf_(bf_one(statB[(gr << 7) + k]) + sbias[r]);
        const float kd = sigmoidf_(bf_one(kdB[(gr << 7) + k]));
        Xl[r][k] = sdisc[r] * (sb - kd) * kn_emb[(gr << 7) + k];
    }
    const int jc = t & 127, rg = t >> 7;    // col-within-half, row-group (16 rows)

    // ---- pn1: 256 output cols in two 128-col halves ----
    for (int half = 0; half < 2; ++half) {
        float acc[16];
#pragma unroll
        for (int i = 0; i < 16; ++i) acc[i] = 0.f;
        for (int k0 = 0; k0 < 128; k0 += 32) {
            __syncthreads();
            for (int idx = t; idx < 128 * 32; idx += 256) {
                int jj = idx >> 5, kp = idx & 31;
                BT[kp][jj] = fabsf(pn1_w[(half * 128 + jj) * 128 + k0 + kp]);
            }
            __syncthreads();
#pragma unroll
            for (int kp = 0; kp < 32; ++kp) {
                float b = BT[kp][jc];
#pragma unroll
                for (int rr = 0; rr < 16; ++rr)
                    acc[rr] += Xl[rg * 16 + rr][k0 + kp] * b;
            }
        }
        const float bj = pn1_b[half * 128 + jc];
#pragma unroll
        for (int rr = 0; rr < 16; ++rr)
            H1[rg * 16 + rr][half * 128 + jc] = sigmoidf_(acc[rr] + bj);
    }

    // ---- pn2: 128 output cols, KK=256 ----
    {
        float acc[16];
#pragma unroll
        for (int i = 0; i < 16; ++i) acc[i] = 0.f;
        for (int k0 = 0; k0 < 256; k0 += 32) {
            __syncthreads();
            for (int idx = t; idx < 128 * 32; idx += 256) {
                int jj = idx >> 5, kp = idx & 31;
                BT[kp][jj] = fabsf(pn2_w[jj * 256 + k0 + kp]);
            }
            __syncthreads();
#pragma unroll
            for (int kp = 0; kp < 32; ++kp) {
                float b = BT[kp][jc];
#pragma unroll
                for (int rr = 0; rr < 16; ++rr)
                    acc[rr] += H1[rg * 16 + rr][k0 + kp] * b;
            }
        }
        const float bj = pn2_b[jc];
#pragma unroll
        for (int rr = 0; rr < 16; ++rr)
            Sv[rg * 16 + rr][jc] = sigmoidf_(acc[rr] + bj);
    }
    __syncthreads();
    // ---- pn3 ----
    if (t < ROWS) {
        float a = 0.f;
#pragma unroll 4
        for (int k = 0; k < 128; ++k) a += Sv[t][k] * wl[k];
        out[row0 + t] = sigmoidf_(a + pn3_b[0]);
    }
}

// ---------------------------------------------------------------------------
// Launch
// ---------------------------------------------------------------------------
static inline size_t align256(size_t x) { return (x + 255) & ~size_t(255); }

extern "C" void kernel_launch(void* const* d_in, const int* in_sizes, int n_in,
                              void* d_out, int out_size, void* d_ws, size_t ws_size,
                              hipStream_t stream) {
    const int*   stu_id   = (const int*)d_in[0];
    const int*   exer_id  = (const int*)d_in[1];
    const float* kn_emb   = (const float*)d_in[2];
    const float* stu_emb  = (const float*)d_in[3];
    const float* exer_emb = (const float*)d_in[4];
    const float* kn_base  = (const float*)d_in[5];
    const float* stu_bias = (const float*)d_in[6];
    const float* e_disc   = (const float*)d_in[7];
    const float* W1_w     = (const float*)d_in[8];
    const float* W1_b     = (const float*)d_in[9];
    const float* W0_w     = (const float*)d_in[10];
    const float* W0_b     = (const float*)d_in[11];
    const float* pn1_w    = (const float*)d_in[12];
    const float* pn1_b    = (const float*)d_in[13];
    const float* pn2_w    = (const float*)d_in[14];
    const float* pn2_b    = (const float*)d_in[15];
    const float* pn3_w    = (const float*)d_in[16];
    const float* pn3_b    = (const float*)d_in[17];
    const int*   ui1_r = (const int*)d_in[18]; const int* ui1_c = (const int*)d_in[19];
    const float* ui1_v = (const float*)d_in[20];
    const int*   iu1_r = (const int*)d_in[21]; const int* iu1_c = (const int*)d_in[22];
    const float* iu1_v = (const float*)d_in[23];
    const int*   ui0_r = (const int*)d_in[24]; const int* ui0_c = (const int*)d_in[25];
    const float* ui0_v = (const float*)d_in[26];
    const int*   iu0_r = (const int*)d_in[27]; const int* iu0_c = (const int*)d_in[28];
    const float* iu0_v = (const float*)d_in[29];
    const float* d_i_1 = (const float*)d_in[30];
    const float* d_j_1 = (const float*)d_in[31];
    const float* d_i_0 = (const float*)d_in[32];
    const float* d_j_0 = (const float*)d_in[33];
    float* out = (float*)d_out;

    typedef unsigned short u16;
    typedef unsigned char u8;
    char* p = (char*)d_ws;
    size_t off = 0;
    auto alloc = [&](size_t bytes) { char* q = p + off; off += align256(bytes); return q; };
    // bf16 state
    u16* stat  = (u16*)alloc(size_t(SN) * KN * 2);
    u16* kdiff = (u16*)alloc(size_t(EN) * KN * 2);
    // fp8 shadows
    u8* st8 = (u8*)alloc(size_t(SN) * KN);
    u8* kd8 = (u8*)alloc(size_t(EN) * KN);
    // aggregation buffers
    u16* as1 = (u16*)alloc(size_t(SN) * KN * 2);
    u16* as0 = (u16*)alloc(size_t(SN) * KN * 2);
    u16* ae1 = (u16*)alloc(size_t(EN) * KN * 2);
    u16* ae0 = (u16*)alloc(size_t(EN) * KN * 2);
    // compact last-layer outputs [BN,128] bf16
    u16* statB = (u16*)alloc(size_t(BN) * KN * 2);
    u16* kdB   = (u16*)alloc(size_t(BN) * KN * 2);
    // bf16 weight tables
    u16* Kb  = (u16*)alloc(size_t(KN) * DN * 2);
    u16* Wb1 = (u16*)alloc(size_t(KN) * KN * 2);
    u16* Wb0 = (u16*)alloc(size_t(KN) * KN * 2);
    // sort structures
    int*  coarseCnt  = (int*)alloc(512 * 4);
    int*  coarseBase = (int*)alloc((NBIN2 + 1) * 4);
    int*  tails      = (int*)alloc(512 * 4);
    int*  rp_all     = (int*)alloc(size_t(NTOT2 + 1) * 4);
    int2* stg        = (int2*)alloc(size_t(4) * NE * 8);
    int2* cv_all     = (int2*)alloc(size_t(4) * NE * 8);
    if (off > ws_size) return;

    CsrB c;
    c.rows[0] = ui1_r; c.cols[0] = ui1_c; c.vals[0] = ui1_v;
    c.rows[1] = ui0_r; c.cols[1] = ui0_c; c.vals[1] = ui0_v;
    c.rows[2] = iu1_r; c.cols[2] = iu1_c; c.vals[2] = iu1_v;
    c.rows[3] = iu0_r; c.cols[3] = iu0_c; c.vals[3] = iu0_v;

    // ---- weight conversions + counter zeroing (one dispatch, runs first) ----
    {
        const int n0 = KN * DN / 2, n1 = KN * KN / 2, n2 = KN * KN / 2;
        f2bf3z<<<(n0 + n1 + n2 + 255) / 256, 256, 0, stream>>>(
            kn_base, Kb, n0, W1_w, Wb1, n1, W0_w, Wb0, n2, coarseCnt);
    }

    // ---- merged: coarse histogram + projections (independent work) ----
    const int nbS = (SN + 63) / 64, nbE = (EN + 63) / 64;
    hist_proj<DN><<<4 * HB + nbS + nbE, 256, 0, stream>>>(
        c, coarseCnt, stu_emb, exer_emb, Kb, stat, st8, kdiff, kd8, nbS);

    // ---- rest of the two-pass partition sort ----
    scan_coarse<<<1, 512, 0, stream>>>(coarseCnt, coarseBase, tails);
    part1<<<4 * PG1, 512, 0, stream>>>(c, tails, stg);
    part2<<<NBIN2, 512, 0, stream>>>(coarseBase, stg, rp_all, cv_all);

    const int nblkS = (SN + 127) / 128, nblkE = (EN + 127) / 128;

    // ---- GCN layers (layers 0,1 full; layer 2 only at gathered rows) ----
    for (int l = 0; l < NLAYER; ++l) {
        if (l < NLAYER - 1) {
            spmm_all<false><<<(SN + EN + 3) / 4, 256, 0, stream>>>(
                rp_all, (const long long*)cv_all, kd8, st8, as1, as0, ae1, ae0,
                nullptr, nullptr);
            gemm2_mfma<false><<<nblkS + nblkE, 512, 0, stream>>>(
                as1, as0, stat, d_i_1, d_i_0, stat, st8,
                ae1, ae0, kdiff, d_j_1, d_j_0, kdiff, kd8,
                Wb1, Wb0, W1_b, W0_b, nullptr, nullptr, nblkS);
        } else {
            // last layer: only rows referenced by the head (compact outputs)
            spmm_all<true><<<(2 * BN) / 4, 256, 0, stream>>>(
                rp_all, (const long long*)cv_all, kd8, st8, as1, as0, ae1, ae0,
                stu_id, exer_id);
            gemm2_mfma<true><<<2 * (BN / 128), 512, 0, stream>>>(
                as1, as0, stat, d_i_1, d_i_0, statB, nullptr,
                ae1, ae0, kdiff, d_j_1, d_j_0, kdB, nullptr,
                Wb1, Wb0, W1_b, W0_b, stu_id, exer_id, BN / 128);
        }
    }

    // ---- entire head in one dispatch ----
    pn_head<<<BN / 32, 256, 0, stream>>>(stu_id, exer_id, kn_emb, statB, kdB,
                                         stu_bias, e_disc, pn1_w, pn1_b,
                                         pn2_w, pn2_b, pn3_w, pn3_b, out);
    (void)out_size; (void)n_in; (void)in_sizes;
}

// Round 8
// 552.879 us; speedup vs baseline: 1.0825x; 1.0825x over previous
//
#include <hip/hip_runtime.h>
#include <hip/hip_bf16.h>

// Problem constants (from reference)
#define SN 50000
#define EN 20000
#define KN 128
#define DN 64
#define BN 4096
#define NE 1000000
#define NLAYER 3

// Column-chunk bucketing: chunk = 4096 gather-table rows (fp8: 0.5MB)
#define CH_SHIFT 12
#define NCH0 5                        // side0 (ui): cols index kdiff, EN -> 5 chunks
#define NCH1 13                       // side1 (iu): cols index stat,  SN -> 13 chunks
// fine bucket = (2*row + tagbit)*nch + chunk   (tagbit 0 = pos, 1 = neg)
#define SIDE1_BASE2 (2 * SN * NCH0)            // 500000
#define NTOT2 (2 * (SN * NCH0 + EN * NCH1))    // 1020000 fine buckets

// Two-pass partition sort
#define BIN_SHIFT 11
#define NBIN2 ((NTOT2 + 2047) >> 11)  // 499 coarse bins (2048 fine buckets each)
#define T1 4096                       // edges per part1 tile
#define PG1 ((NE + T1 - 1) / T1)      // 245 tiles per adjacency
#define HB 256                        // hist blocks per adjacency

typedef float f32x4 __attribute__((ext_vector_type(4)));
typedef float f32x2 __attribute__((ext_vector_type(2)));
typedef short bf16x8 __attribute__((ext_vector_type(8)));

__device__ __forceinline__ float sigmoidf_(float v) { return 1.f / (1.f + __expf(-v)); }
__device__ __forceinline__ float bf_lo(unsigned u) { return __uint_as_float(u << 16); }
__device__ __forceinline__ float bf_hi(unsigned u) { return __uint_as_float(u & 0xffff0000u); }
__device__ __forceinline__ float bf_one(unsigned short s) { return __uint_as_float((unsigned)s << 16); }
__device__ __forceinline__ unsigned packbf2(float a, float b) {
    __hip_bfloat16 ha = __float2bfloat16(a), hb = __float2bfloat16(b);
    unsigned short ua = *(unsigned short*)&ha, ub = *(unsigned short*)&hb;
    return (unsigned)ua | ((unsigned)ub << 16);
}
__device__ __forceinline__ unsigned short packbf1(float a) {
    __hip_bfloat16 ha = __float2bfloat16(a);
    return *(unsigned short*)&ha;
}
// fp8(e4m3) of a bf16 value — matches the old bf2fp8 two-step numerics
__device__ __forceinline__ unsigned char fp8_of_bf16(unsigned short h) {
    float f = bf_one(h);
    int pk = __builtin_amdgcn_cvt_pk_fp8_f32(f, f, 0, false);
    return (unsigned char)(pk & 0xff);
}

struct CsrB {
    const int* rows[4]; const int* cols[4]; const float* vals[4];
};

__device__ __forceinline__ int bucket_idx(int a, int r, int cc) {
    int side = a >> 1;
    int nch = side ? NCH1 : NCH0;
    int base = side ? SIDE1_BASE2 : 0;
    int tb = a & 1;                    // a=0,2 pos (first); a=1,3 neg (second)
    return base + (2 * r + tb) * nch + (cc >> CH_SHIFT);
}

// ---------------------------------------------------------------------------
// MERGED: coarse histogram (blocks 0..4*HB-1) + projection MFMA GEMM
// (remaining blocks). Independent work; one dispatch slot saved.
// ---------------------------------------------------------------------------
template <int KK>
__global__ __launch_bounds__(256) void hist_proj(
    CsrB c, int* __restrict__ cnt,
    const float* __restrict__ XS, const float* __restrict__ XE,
    const unsigned short* __restrict__ W,
    unsigned short* __restrict__ outS, unsigned char* __restrict__ f8S,
    unsigned short* __restrict__ outE, unsigned char* __restrict__ f8E,
    int nbS) {
    constexpr int PITCH = KK + 8;
    __shared__ int h[512];
    __shared__ unsigned short Wl[128 * PITCH];
    const int t = threadIdx.x;

    if ((int)blockIdx.x < 4 * HB) {
        // ---------------- histogram part ----------------
        h[t] = 0; h[t + 256] = 0;
        __syncthreads();
        const int a = blockIdx.x >> 8;
        const int tile = blockIdx.x & 255;
        const int per = (NE + HB - 1) / HB;
        const int beg = tile * per, end = min(beg + per, NE);
        for (int i = beg + t; i < end; i += 256)
            atomicAdd(&h[bucket_idx(a, c.rows[a][i], c.cols[a][i]) >> BIN_SHIFT], 1);
        __syncthreads();
        if (h[t]) atomicAdd(&cnt[t], h[t]);
        if (h[t + 256]) atomicAdd(&cnt[t + 256], h[t + 256]);
        return;
    }
    // ---------------- projection part ----------------
    const int bid = (int)blockIdx.x - 4 * HB;
    for (int idx = t * 8; idx < 128 * KK; idx += 2048) {
        int r = idx / KK, k = idx - r * KK;
        *(uint4*)(&Wl[r * PITCH + k]) = *(const uint4*)(&W[idx]);
    }
    __syncthreads();
    const bool sideE = bid >= nbS;
    const float* X = sideE ? XE : XS;
    unsigned short* out = sideE ? outE : outS;
    unsigned char* f8 = sideE ? f8E : f8S;
    const int M = sideE ? EN : SN;
    const int lane = t & 63;
    const int nm = lane & 15;
    const int quad = lane >> 4;
    const int row0 = (bid - (sideE ? nbS : 0)) * 64 + (t >> 6) * 16;
    if (row0 >= M) return;

    f32x4 acc[8];
#pragma unroll
    for (int nt = 0; nt < 8; ++nt) acc[nt] = (f32x4){0.f, 0.f, 0.f, 0.f};

    const float* xrow = X + (size_t)(row0 + nm) * KK + quad * 8;
#pragma unroll
    for (int ks = 0; ks < KK / 32; ++ks) {
        float4 f0 = *(const float4*)(xrow + ks * 32);
        float4 f1 = *(const float4*)(xrow + ks * 32 + 4);
        unsigned q[4] = {packbf2(f0.x, f0.y), packbf2(f0.z, f0.w),
                         packbf2(f1.x, f1.y), packbf2(f1.z, f1.w)};
        bf16x8 a = *(bf16x8*)q;
#pragma unroll
        for (int nt = 0; nt < 8; ++nt) {
            bf16x8 b = *(const bf16x8*)(&Wl[(nt * 16 + nm) * PITCH + ks * 32 + quad * 8]);
            acc[nt] = __builtin_amdgcn_mfma_f32_16x16x32_bf16(a, b, acc[nt], 0, 0, 0);
        }
    }
    const size_t obase = (size_t)(row0 + quad * 4) * 128 + nm;
    unsigned short* orow = out + obase;
    unsigned char* frow = f8 + obase;
#pragma unroll
    for (int r = 0; r < 4; ++r)
#pragma unroll
        for (int nt = 0; nt < 8; ++nt) {
            unsigned short hh = packbf1(acc[nt][r]);
            orow[(size_t)r * 128 + nt * 16] = hh;
            frow[(size_t)r * 128 + nt * 16] = fp8_of_bf16(hh);
        }
}

// 1-block exclusive scan of coarse counts -> base[NBIN2+1] and tails[NBIN2]
__global__ __launch_bounds__(512) void scan_coarse(const int* __restrict__ cnt,
                                                   int* __restrict__ base,
                                                   int* __restrict__ tails) {
    __shared__ int sh[512];
    const int t = threadIdx.x;
    const int v = (t < NBIN2) ? cnt[t] : 0;
    sh[t] = v;
    __syncthreads();
    for (int o = 1; o < 512; o <<= 1) {
        int x = sh[t]; int u = (t >= o) ? sh[t - o] : 0;
        __syncthreads(); sh[t] = x + u; __syncthreads();
    }
    if (t < NBIN2) {
        const int ex = sh[t] - v;
        base[t] = ex;
        tails[t] = ex;
    }
    if (t == 511) base[NBIN2] = sh[511];
}

// ---------------------------------------------------------------------------
// part1: multisplit edges into coarse-bin segments with coalesced writes.
// Record int2: .x = col(0..15) | fine_bucket_low11(17..27), .y = f32 val (plain)
// ---------------------------------------------------------------------------
__global__ __launch_bounds__(512) void part1(CsrB c, int* __restrict__ tails,
                                             int2* __restrict__ stg) {
    __shared__ int2 srec[T1];
    __shared__ unsigned short sbin[T1];
    __shared__ int h[512], offs[512], gbase[512], sc[512];
    const int t = threadIdx.x;
    const int a = blockIdx.x / PG1;
    const int tile = blockIdx.x - a * PG1;
    const int beg = tile * T1;
    const int cnt = min(T1, NE - beg);
    h[t] = 0;
    __syncthreads();

    int2 rec[8]; int rbin[8]; int rrank[8];
#pragma unroll
    for (int k = 0; k < 8; ++k) {
        int o = t + k * 512;
        if (o < cnt) {
            int i = beg + o;
            int cc = c.cols[a][i];
            int B = bucket_idx(a, c.rows[a][i], cc);
            int bin = B >> BIN_SHIFT;
            rec[k] = make_int2(cc | ((B & 2047) << 17), __float_as_int(c.vals[a][i]));
            rbin[k] = bin;
            rrank[k] = atomicAdd(&h[bin], 1);
        } else {
            rbin[k] = -1;
        }
    }
    __syncthreads();
    sc[t] = h[t];
    __syncthreads();
    for (int o = 1; o < 512; o <<= 1) {
        int x = sc[t]; int u = (t >= o) ? sc[t - o] : 0;
        __syncthreads(); sc[t] = x + u; __syncthreads();
    }
    offs[t] = sc[t] - h[t];
    if (h[t] > 0) gbase[t] = atomicAdd(&tails[t], h[t]);
    __syncthreads();
#pragma unroll
    for (int k = 0; k < 8; ++k) {
        if (rbin[k] >= 0) {
            int pos = offs[rbin[k]] + rrank[k];
            srec[pos] = rec[k];
            sbin[pos] = (unsigned short)rbin[k];
        }
    }
    __syncthreads();
    for (int idx = t; idx < cnt; idx += 512) {
        int b = sbin[idx];
        stg[gbase[b] + (idx - offs[b])] = srec[idx];
    }
}

// ---------------------------------------------------------------------------
// part2: one block per coarse bin. Builds fine histogram+prefix in LDS
// (producing rp_all), then scatters into the bin's own ~128KB window.
// cv record: .x = bare column, .y = f32 value
// ---------------------------------------------------------------------------
__global__ __launch_bounds__(512) void part2(const int* __restrict__ coarseBase,
                                             const int2* __restrict__ stg,
                                             int* __restrict__ rp,
                                             int2* __restrict__ cv) {
    __shared__ int cnt2[2048];
    __shared__ int tsum[512];
    const int b = blockIdx.x;
    const int t = threadIdx.x;
    const int fineBase = b << BIN_SHIFT;
    const int nf = min(2048, NTOT2 - fineBase);
    const int segBeg = coarseBase[b];
    const int segEnd = coarseBase[b + 1];
    for (int i = t; i < 2048; i += 512) cnt2[i] = 0;
    __syncthreads();
    for (int e = segBeg + t; e < segEnd; e += 512)
        atomicAdd(&cnt2[((unsigned)stg[e].x) >> 17], 1);
    __syncthreads();
    const int i4 = t * 4;
    int v0 = cnt2[i4], v1 = cnt2[i4 + 1], v2 = cnt2[i4 + 2], v3 = cnt2[i4 + 3];
    tsum[t] = v0 + v1 + v2 + v3;
    __syncthreads();
    for (int o = 1; o < 512; o <<= 1) {
        int x = tsum[t]; int u = (t >= o) ? tsum[t - o] : 0;
        __syncthreads(); tsum[t] = x + u; __syncthreads();
    }
    const int pre = (t == 0) ? 0 : tsum[t - 1];
    const int p0 = pre, p1 = pre + v0, p2 = p1 + v1, p3 = p2 + v2;
    cnt2[i4] = p0; cnt2[i4 + 1] = p1; cnt2[i4 + 2] = p2; cnt2[i4 + 3] = p3;
    if (i4 + 0 < nf) rp[fineBase + i4 + 0] = segBeg + p0;
    if (i4 + 1 < nf) rp[fineBase + i4 + 1] = segBeg + p1;
    if (i4 + 2 < nf) rp[fineBase + i4 + 2] = segBeg + p2;
    if (i4 + 3 < nf) rp[fineBase + i4 + 3] = segBeg + p3;
    if (b == NBIN2 - 1 && t == 511) rp[NTOT2] = segEnd;
    __syncthreads();
    for (int e = segBeg + t; e < segEnd; e += 512) {
        int2 r = stg[e];
        int pos = segBeg + atomicAdd(&cnt2[((unsigned)r.x) >> 17], 1);
        cv[pos] = make_int2(r.x & 0xFFFF, r.y);
    }
}

// ---------------------------------------------------------------------------
// fp32 -> bf16 conversion, all three weight tables in ONE dispatch.
// Also zeroes the coarse-histogram counters (stream-ordered before hist).
// ---------------------------------------------------------------------------
__global__ __launch_bounds__(256) void f2bf3z(
    const float* __restrict__ s0, unsigned short* __restrict__ d0, int n0,
    const float* __restrict__ s1, unsigned short* __restrict__ d1, int n1,
    const float* __restrict__ s2, unsigned short* __restrict__ d2, int n2,
    int* __restrict__ coarseCnt) {
    int j = blockIdx.x * 256 + threadIdx.x;
    if (j < 512) coarseCnt[j] = 0;
    const float* s; unsigned short* d;
    if (j < n0) { s = s0; d = d0; }
    else {
        j -= n0;
        if (j < n1) { s = s1; d = d1; }
        else {
            j -= n1;
            if (j >= n2) return;
            s = s2; d = d2;
        }
    }
    float2 f = ((const float2*)s)[j];
    ((unsigned*)d)[j] = packbf2(f.x, f.y);
}

// ---------------------------------------------------------------------------
// Fused dual-weight MFMA GEMM, BOTH sides in one dispatch (in-place safe):
//   out = (agg1 + d1.*y)@W1^T + (agg0 + d0.*y)@W0^T + (b1+b0)
// 512 threads / 128 rows per block. Full mode also writes the fp8 shadow
// inline. LIST mode (last layer): block processes 128 *list entries*;
// aggregation buffers compact [BN,128]; y,d gathered through ids; compact
// output (race-free under duplicate ids, bitwise-identical math).
// ---------------------------------------------------------------------------
template <bool LIST>
__global__ __launch_bounds__(512) void gemm2_mfma(
    const unsigned short* __restrict__ agg1S, const unsigned short* __restrict__ agg0S,
    const unsigned short* __restrict__ yS,
    const float* __restrict__ d1S, const float* __restrict__ d0S,
    unsigned short* __restrict__ outS, unsigned char* __restrict__ f8S,
    const unsigned short* __restrict__ agg1E, const unsigned short* __restrict__ agg0E,
    const unsigned short* __restrict__ yE,
    const float* __restrict__ d1E, const float* __restrict__ d0E,
    unsigned short* __restrict__ outE, unsigned char* __restrict__ f8E,
    const unsigned short* __restrict__ W1, const unsigned short* __restrict__ W0,
    const float* __restrict__ b1, const float* __restrict__ b0,
    const int* __restrict__ idsS, const int* __restrict__ idsE, int nblkS) {
    constexpr int PITCH = 136;
    __shared__ unsigned short Wl[2 * 128 * PITCH];
    const int t = threadIdx.x;
    for (int idx = t * 8; idx < 128 * 128; idx += 4096) {
        int r = idx >> 7, k = idx & 127;
        *(uint4*)(&Wl[r * PITCH + k]) = *(const uint4*)(&W1[idx]);
        *(uint4*)(&Wl[128 * PITCH + r * PITCH + k]) = *(const uint4*)(&W0[idx]);
    }
    __syncthreads();
    const bool sideE = (int)blockIdx.x >= nblkS;
    const unsigned short* agg1 = sideE ? agg1E : agg1S;
    const unsigned short* agg0 = sideE ? agg0E : agg0S;
    const unsigned short* y    = sideE ? yE : yS;
    const float* d1 = sideE ? d1E : d1S;
    const float* d0 = sideE ? d0E : d0S;
    unsigned short* out = sideE ? outE : outS;
    unsigned char* f8 = sideE ? f8E : f8S;
    const int M = LIST ? BN : (sideE ? EN : SN);
    const int lane = t & 63;
    const int nm = lane & 15;
    const int quad = lane >> 4;
    const int row0 = ((int)blockIdx.x - (sideE ? nblkS : 0)) * 128 + (t >> 6) * 16;
    if (row0 >= M) return;

    const int lrow = row0 + nm;                  // list index (LIST) or row
    int grow = lrow;                             // real row for y / d gathers
    if (LIST) grow = (sideE ? idsE : idsS)[lrow];

    const float d1v = d1[grow];
    const float d0v = d0[grow];

    f32x4 acc[8];
#pragma unroll
    for (int nt = 0; nt < 8; ++nt) acc[nt] = (f32x4){0.f, 0.f, 0.f, 0.f};

    const size_t rbA = (size_t)lrow * 128 + quad * 8;   // aggs: compact in LIST
    const size_t rbY = (size_t)grow * 128 + quad * 8;   // y: gathered in LIST
#pragma unroll
    for (int ks = 0; ks < 4; ++ks) {
        uint4 ua1 = *(const uint4*)(agg1 + rbA + ks * 32);
        uint4 ua0 = *(const uint4*)(agg0 + rbA + ks * 32);
        uint4 uy  = *(const uint4*)(y    + rbY + ks * 32);
        uint4 p1, p0;
        {
            unsigned* a1 = (unsigned*)&ua1; unsigned* a0 = (unsigned*)&ua0;
            unsigned* yy = (unsigned*)&uy;
            unsigned* q1 = (unsigned*)&p1; unsigned* q0 = (unsigned*)&p0;
#pragma unroll
            for (int w = 0; w < 4; ++w) {
                float ylo = bf_lo(yy[w]), yhi = bf_hi(yy[w]);
                q1[w] = packbf2(bf_lo(a1[w]) + d1v * ylo, bf_hi(a1[w]) + d1v * yhi);
                q0[w] = packbf2(bf_lo(a0[w]) + d0v * ylo, bf_hi(a0[w]) + d0v * yhi);
            }
        }
        bf16x8 af1 = *(bf16x8*)&p1;
        bf16x8 af0 = *(bf16x8*)&p0;
#pragma unroll
        for (int nt = 0; nt < 8; ++nt) {
            bf16x8 bw1 = *(const bf16x8*)(&Wl[(nt * 16 + nm) * PITCH + ks * 32 + quad * 8]);
            acc[nt] = __builtin_amdgcn_mfma_f32_16x16x32_bf16(af1, bw1, acc[nt], 0, 0, 0);
            bf16x8 bw0 = *(const bf16x8*)(&Wl[128 * PITCH + (nt * 16 + nm) * PITCH + ks * 32 + quad * 8]);
            acc[nt] = __builtin_amdgcn_mfma_f32_16x16x32_bf16(af0, bw0, acc[nt], 0, 0, 0);
        }
    }
    const size_t obase = (size_t)(row0 + quad * 4) * 128 + nm;
    unsigned short* orow = out + obase;
    unsigned char* frow = f8 + obase;
#pragma unroll
    for (int nt = 0; nt < 8; ++nt) {
        float bb = b1[nt * 16 + nm] + b0[nt * 16 + nm];
#pragma unroll
        for (int r = 0; r < 4; ++r) {
            unsigned short h = packbf1(acc[nt][r] + bb);
            orow[(size_t)r * 128 + nt * 16] = h;
            if (!LIST) frow[(size_t)r * 128 + nt * 16] = fp8_of_bf16(h);
        }
    }
}

// ---------------------------------------------------------------------------
// Quad-SPMM (round-1/3 form — empirical floor of all structural variants
// tried in rounds 2/4/5): 4 edges per wave instruction. Quarter-wave q
// handles edge e+q; lane c (0..15) covers cols 8c..8c+7 via one uint2 fp8
// gather + 4 cvt_pk_f32_fp8 + 4 packed-f32 FMAs. Tag phases serial (keeps
// one gather-table window live per wave; mixing thrashed per-XCD L2).
// Cross-quarter reduce via shfl_xor(16|32); quarter 0 writes the pos row,
// quarter 1 the neg row (16 lanes x 16B coalesced).
// LIST mode (last layer): only 2*BN waves; wave i handles row ids[i] and
// writes compact output row i (race-free under duplicate ids).
// ---------------------------------------------------------------------------
template <bool LIST>
__global__ __launch_bounds__(256) void spmm_all(
    const int* __restrict__ rp, const long long* __restrict__ cv,
    const unsigned char* __restrict__ kd8, const unsigned char* __restrict__ st8,
    unsigned short* __restrict__ as1, unsigned short* __restrict__ as0,
    unsigned short* __restrict__ ae1, unsigned short* __restrict__ ae0,
    const int* __restrict__ idsS, const int* __restrict__ idsE) {
    const int wave = (blockIdx.x * 256 + threadIdx.x) >> 6;
    const int lane = threadIdx.x & 63;
    const int NW = LIST ? 2 * BN : SN + EN;
    if (wave >= NW) return;
    const bool sideE = LIST ? (wave >= BN) : (wave >= SN);
    const int li = sideE ? (wave - (LIST ? BN : SN)) : wave;
    const int r = LIST ? (sideE ? idsE[li] : idsS[li]) : li;
    const int nch = sideE ? NCH1 : NCH0;
    const int* rpb = rp + (sideE ? SIDE1_BASE2 : 0);
    const int q = lane >> 4;           // quarter 0..3 -> edge e+q
    const int c = lane & 15;           // col group: cols 8c..8c+7
    const unsigned char* g8 = (sideE ? st8 : kd8) + c * 8;

    const int rbase = 2 * r * nch;
    const int e0 = rpb[rbase];
    const int em = rpb[rbase + nch];
    const int ee = rpb[rbase + 2 * nch];

    f32x2 accP[4], accN[4];
#pragma unroll
    for (int j = 0; j < 4; ++j) { accP[j] = (f32x2){0.f, 0.f}; accN[j] = (f32x2){0.f, 0.f}; }

#define QUAD(E, ACC)                                                        \
    {                                                                       \
        int col = (int)((E) & 0xFFFF);                                      \
        float v = __int_as_float((int)((E) >> 32));                         \
        f32x2 vv = {v, v};                                                  \
        uint2 u = *(const uint2*)(g8 + (col << 7));                         \
        ACC[0] += vv * __builtin_amdgcn_cvt_pk_f32_fp8((int)u.x, false);    \
        ACC[1] += vv * __builtin_amdgcn_cvt_pk_f32_fp8((int)u.x, true);     \
        ACC[2] += vv * __builtin_amdgcn_cvt_pk_f32_fp8((int)u.y, false);    \
        ACC[3] += vv * __builtin_amdgcn_cvt_pk_f32_fp8((int)u.y, true);     \
    }

    // phase 1: pos edges [e0, em)
    {
        int e = e0;
        for (; e + 16 <= em; e += 16) {
            long long E0 = cv[e + q];
            long long E1 = cv[e + 4 + q];
            long long E2 = cv[e + 8 + q];
            long long E3 = cv[e + 12 + q];
            QUAD(E0, accP) QUAD(E1, accP) QUAD(E2, accP) QUAD(E3, accP)
        }
        for (; e + 4 <= em; e += 4) {
            long long E0 = cv[e + q];
            QUAD(E0, accP)
        }
        if (e < em) {
            int idx = min(e + q, em - 1);
            long long E0 = cv[idx];
            if (e + q >= em) E0 &= 0xFFFFLL;   // keep col, zero value
            QUAD(E0, accP)
        }
    }
    // phase 2: neg edges [em, ee)
    {
        int e = em;
        for (; e + 16 <= ee; e += 16) {
            long long E0 = cv[e + q];
            long long E1 = cv[e + 4 + q];
            long long E2 = cv[e + 8 + q];
            long long E3 = cv[e + 12 + q];
            QUAD(E0, accN) QUAD(E1, accN) QUAD(E2, accN) QUAD(E3, accN)
        }
        for (; e + 4 <= ee; e += 4) {
            long long E0 = cv[e + q];
            QUAD(E0, accN)
        }
        if (e < ee) {
            int idx = min(e + q, ee - 1);
            long long E0 = cv[idx];
            if (e + q >= ee) E0 &= 0xFFFFLL;
            QUAD(E0, accN)
        }
    }
#undef QUAD

    // reduce over quarters (xor 16, then 32)
#pragma unroll
    for (int j = 0; j < 4; ++j) {
        accP[j].x += __shfl_xor(accP[j].x, 16);
        accP[j].y += __shfl_xor(accP[j].y, 16);
        accN[j].x += __shfl_xor(accN[j].x, 16);
        accN[j].y += __shfl_xor(accN[j].y, 16);
        accP[j].x += __shfl_xor(accP[j].x, 32);
        accP[j].y += __shfl_xor(accP[j].y, 32);
        accN[j].x += __shfl_xor(accN[j].x, 32);
        accN[j].y += __shfl_xor(accN[j].y, 32);
    }
    unsigned short* o1 = sideE ? ae1 : as1;
    unsigned short* o0 = sideE ? ae0 : as0;
    const int oi = LIST ? li : r;      // compact slot in LIST mode
    const int base = (oi << 7) + c * 8;
    if (q == 0) {
        uint4 w;
        w.x = packbf2(accP[0].x, accP[0].y);
        w.y = packbf2(accP[1].x, accP[1].y);
        w.z = packbf2(accP[2].x, accP[2].y);
        w.w = packbf2(accP[3].x, accP[3].y);
        *(uint4*)&o1[base] = w;
    } else if (q == 1) {
        uint4 w;
        w.x = packbf2(accN[0].x, accN[0].y);
        w.y = packbf2(accN[1].x, accN[1].y);
        w.z = packbf2(accN[2].x, accN[2].y);
        w.w = packbf2(accN[3].x, accN[3].y);
        *(uint4*)&o0[base] = w;
    }
}

// ---------------------------------------------------------------------------
// pn1 fused with head1 — ROWS=8 (512 blocks, 2x the round-6 parallelism;
// pn_head's 107us @ 5.6% occupancy showed the head is CU-coverage bound).
// x computed inline during staging; h1 = sig(x @ |pn1_w|^T + pn1_b).
// Per-output accumulation is plain ascending k -> bitwise-identical.
// ---------------------------------------------------------------------------
__global__ __launch_bounds__(256) void pn1_fused(
    const int* __restrict__ stu_id, const int* __restrict__ exer_id,
    const float* __restrict__ kn_emb, const unsigned short* __restrict__ statB,
    const unsigned short* __restrict__ kdB, const float* __restrict__ stu_bias,
    const float* __restrict__ e_disc,
    const float* __restrict__ W, const float* __restrict__ bias,
    float* __restrict__ out) {
    constexpr int KK = 128, NCOLS = 256, ROWS = 8, KP = 32;
    __shared__ float BT[KP * (NCOLS + 1)];
    __shared__ float Xl[ROWS * (KK + 1)];
    __shared__ float sdisc[ROWS], sbias[ROWS];
    const int t = threadIdx.x;
    const int row0 = blockIdx.x * ROWS;
    if (t < ROWS) {
        const int gr = row0 + t;
        sdisc[t] = sigmoidf_(e_disc[exer_id[gr]]);
        sbias[t] = stu_bias[stu_id[gr]];
    }
    __syncthreads();
    for (int idx = t; idx < ROWS * KK; idx += 256) {
        const int r = idx >> 7, k = idx & 127;
        const int gr = row0 + r;
        const float sb = sigmoidf_(bf_one(statB[(gr << 7) + k]) + sbias[r]);
        const float kd = sigmoidf_(bf_one(kdB[(gr << 7) + k]));
        Xl[r * (KK + 1) + k] = sdisc[r] * (sb - kd) * kn_emb[(gr << 7) + k];
    }
    const int j = t;                   // NCOLS == blockDim
    float acc[ROWS];
#pragma unroll
    for (int i = 0; i < ROWS; ++i) acc[i] = 0.f;

    for (int k0 = 0; k0 < KK; k0 += KP) {
        __syncthreads();
        for (int idx = t; idx < NCOLS * KP; idx += 256) {
            int jj = idx / KP, kp = idx % KP;
            BT[kp * (NCOLS + 1) + jj] = fabsf(W[jj * KK + k0 + kp]);
        }
        __syncthreads();
#pragma unroll
        for (int kp = 0; kp < KP; ++kp) {
            float b = BT[kp * (NCOLS + 1) + j];
#pragma unroll
            for (int rr = 0; rr < ROWS; ++rr)
                acc[rr] += Xl[rr * (KK + 1) + k0 + kp] * b;
        }
    }
    const float bj = bias[j];
#pragma unroll
    for (int rr = 0; rr < ROWS; ++rr)
        out[(row0 + rr) * NCOLS + j] = sigmoidf_(acc[rr] + bj);
}

// ---------------------------------------------------------------------------
// pn2 fused with pn3 — ROWS=16 (256 blocks, 2x the round-6 parallelism).
// h2 = sig(h1 @ |pn2_w|^T + pn2_b) kept in LDS; out = sig(h2.|pn3_w|+b3).
// Per-output accumulation is plain ascending k -> bitwise-identical.
// ---------------------------------------------------------------------------
__global__ __launch_bounds__(256) void pn23_fused(
    const float* __restrict__ X, const float* __restrict__ W,
    const float* __restrict__ bias, const float* __restrict__ w3,
    const float* __restrict__ b3, float* __restrict__ out) {
    constexpr int KK = 256, NCOLS = 128, ROWS = 16, KP = 32;
    constexpr int RT = 8;              // NG = 2
    __shared__ float BT[KP * (NCOLS + 1)];
    __shared__ float Xl[ROWS * (KK + 1)];
    __shared__ float Sv[ROWS][NCOLS + 1];
    __shared__ float wl[128];
    const int t = threadIdx.x;
    const int j = t % NCOLS;
    const int rg = t / NCOLS;
    const int row0 = blockIdx.x * ROWS;
    if (t < 128) wl[t] = fabsf(w3[t]);

    for (int idx = t; idx < ROWS * KK; idx += 256) {
        const int r = idx >> 8, k = idx & 255;
        Xl[r * (KK + 1) + k] = X[(row0 + r) * KK + k];
    }
    float acc[RT];
#pragma unroll
    for (int i = 0; i < RT; ++i) acc[i] = 0.f;

    for (int k0 = 0; k0 < KK; k0 += KP) {
        __syncthreads();
        for (int idx = t; idx < NCOLS * KP; idx += 256) {
            int jj = idx / KP, kp = idx % KP;
            BT[kp * (NCOLS + 1) + jj] = fabsf(W[jj * KK + k0 + kp]);
        }
        __syncthreads();
#pragma unroll
        for (int kp = 0; kp < KP; ++kp) {
            float b = BT[kp * (NCOLS + 1) + j];
#pragma unroll
            for (int rr = 0; rr < RT; ++rr)
                acc[rr] += Xl[(rg * RT + rr) * (KK + 1) + k0 + kp] * b;
        }
    }
    const float bj = bias[j];
#pragma unroll
    for (int rr = 0; rr < RT; ++rr)
        Sv[rg * RT + rr][j] = sigmoidf_(acc[rr] + bj);
    __syncthreads();
    if (t < ROWS) {
        float a = 0.f;
#pragma unroll 4
        for (int k = 0; k < 128; ++k) a += Sv[t][k] * wl[k];
        out[row0 + t] = sigmoidf_(a + b3[0]);
    }
}

// ---------------------------------------------------------------------------
// Launch
// ---------------------------------------------------------------------------
static inline size_t align256(size_t x) { return (x + 255) & ~size_t(255); }

extern "C" void kernel_launch(void* const* d_in, const int* in_sizes, int n_in,
                              void* d_out, int out_size, void* d_ws, size_t ws_size,
                              hipStream_t stream) {
    const int*   stu_id   = (const int*)d_in[0];
    const int*   exer_id  = (const int*)d_in[1];
    const float* kn_emb   = (const float*)d_in[2];
    const float* stu_emb  = (const float*)d_in[3];
    const float* exer_emb = (const float*)d_in[4];
    const float* kn_base  = (const float*)d_in[5];
    const float* stu_bias = (const float*)d_in[6];
    const float* e_disc   = (const float*)d_in[7];
    const float* W1_w     = (const float*)d_in[8];
    const float* W1_b     = (const float*)d_in[9];
    const float* W0_w     = (const float*)d_in[10];
    const float* W0_b     = (const float*)d_in[11];
    const float* pn1_w    = (const float*)d_in[12];
    const float* pn1_b    = (const float*)d_in[13];
    const float* pn2_w    = (const float*)d_in[14];
    const float* pn2_b    = (const float*)d_in[15];
    const float* pn3_w    = (const float*)d_in[16];
    const float* pn3_b    = (const float*)d_in[17];
    const int*   ui1_r = (const int*)d_in[18]; const int* ui1_c = (const int*)d_in[19];
    const float* ui1_v = (const float*)d_in[20];
    const int*   iu1_r = (const int*)d_in[21]; const int* iu1_c = (const int*)d_in[22];
    const float* iu1_v = (const float*)d_in[23];
    const int*   ui0_r = (const int*)d_in[24]; const int* ui0_c = (const int*)d_in[25];
    const float* ui0_v = (const float*)d_in[26];
    const int*   iu0_r = (const int*)d_in[27]; const int* iu0_c = (const int*)d_in[28];
    const float* iu0_v = (const float*)d_in[29];
    const float* d_i_1 = (const float*)d_in[30];
    const float* d_j_1 = (const float*)d_in[31];
    const float* d_i_0 = (const float*)d_in[32];
    const float* d_j_0 = (const float*)d_in[33];
    float* out = (float*)d_out;

    typedef unsigned short u16;
    typedef unsigned char u8;
    char* p = (char*)d_ws;
    size_t off = 0;
    auto alloc = [&](size_t bytes) { char* q = p + off; off += align256(bytes); return q; };
    // bf16 state
    u16* stat  = (u16*)alloc(size_t(SN) * KN * 2);
    u16* kdiff = (u16*)alloc(size_t(EN) * KN * 2);
    // fp8 shadows
    u8* st8 = (u8*)alloc(size_t(SN) * KN);
    u8* kd8 = (u8*)alloc(size_t(EN) * KN);
    // aggregation buffers
    u16* as1 = (u16*)alloc(size_t(SN) * KN * 2);
    u16* as0 = (u16*)alloc(size_t(SN) * KN * 2);
    u16* ae1 = (u16*)alloc(size_t(EN) * KN * 2);
    u16* ae0 = (u16*)alloc(size_t(EN) * KN * 2);
    // compact last-layer outputs [BN,128] bf16
    u16* statB = (u16*)alloc(size_t(BN) * KN * 2);
    u16* kdB   = (u16*)alloc(size_t(BN) * KN * 2);
    // bf16 weight tables
    u16* Kb  = (u16*)alloc(size_t(KN) * DN * 2);
    u16* Wb1 = (u16*)alloc(size_t(KN) * KN * 2);
    u16* Wb0 = (u16*)alloc(size_t(KN) * KN * 2);
    // sort structures
    int*  coarseCnt  = (int*)alloc(512 * 4);
    int*  coarseBase = (int*)alloc((NBIN2 + 1) * 4);
    int*  tails      = (int*)alloc(512 * 4);
    int*  rp_all     = (int*)alloc(size_t(NTOT2 + 1) * 4);
    int2* stg        = (int2*)alloc(size_t(4) * NE * 8);
    int2* cv_all     = (int2*)alloc(size_t(4) * NE * 8);
    // head intermediate
    float* h1 = (float*)alloc(size_t(BN) * 256 * 4);
    if (off > ws_size) return;

    CsrB c;
    c.rows[0] = ui1_r; c.cols[0] = ui1_c; c.vals[0] = ui1_v;
    c.rows[1] = ui0_r; c.cols[1] = ui0_c; c.vals[1] = ui0_v;
    c.rows[2] = iu1_r; c.cols[2] = iu1_c; c.vals[2] = iu1_v;
    c.rows[3] = iu0_r; c.cols[3] = iu0_c; c.vals[3] = iu0_v;

    // ---- weight conversions + counter zeroing (one dispatch, runs first) ----
    {
        const int n0 = KN * DN / 2, n1 = KN * KN / 2, n2 = KN * KN / 2;
        f2bf3z<<<(n0 + n1 + n2 + 255) / 256, 256, 0, stream>>>(
            kn_base, Kb, n0, W1_w, Wb1, n1, W0_w, Wb0, n2, coarseCnt);
    }

    // ---- merged: coarse histogram + projections (independent work) ----
    const int nbS = (SN + 63) / 64, nbE = (EN + 63) / 64;
    hist_proj<DN><<<4 * HB + nbS + nbE, 256, 0, stream>>>(
        c, coarseCnt, stu_emb, exer_emb, Kb, stat, st8, kdiff, kd8, nbS);

    // ---- rest of the two-pass partition sort ----
    scan_coarse<<<1, 512, 0, stream>>>(coarseCnt, coarseBase, tails);
    part1<<<4 * PG1, 512, 0, stream>>>(c, tails, stg);
    part2<<<NBIN2, 512, 0, stream>>>(coarseBase, stg, rp_all, cv_all);

    const int nblkS = (SN + 127) / 128, nblkE = (EN + 127) / 128;

    // ---- GCN layers (layers 0,1 full; layer 2 only at gathered rows) ----
    for (int l = 0; l < NLAYER; ++l) {
        if (l < NLAYER - 1) {
            spmm_all<false><<<(SN + EN + 3) / 4, 256, 0, stream>>>(
                rp_all, (const long long*)cv_all, kd8, st8, as1, as0, ae1, ae0,
                nullptr, nullptr);
            gemm2_mfma<false><<<nblkS + nblkE, 512, 0, stream>>>(
                as1, as0, stat, d_i_1, d_i_0, stat, st8,
                ae1, ae0, kdiff, d_j_1, d_j_0, kdiff, kd8,
                Wb1, Wb0, W1_b, W0_b, nullptr, nullptr, nblkS);
        } else {
            // last layer: only rows referenced by the head (compact outputs)
            spmm_all<true><<<(2 * BN) / 4, 256, 0, stream>>>(
                rp_all, (const long long*)cv_all, kd8, st8, as1, as0, ae1, ae0,
                stu_id, exer_id);
            gemm2_mfma<true><<<2 * (BN / 128), 512, 0, stream>>>(
                as1, as0, stat, d_i_1, d_i_0, statB, nullptr,
                ae1, ae0, kdiff, d_j_1, d_j_0, kdB, nullptr,
                Wb1, Wb0, W1_b, W0_b, stu_id, exer_id, BN / 128);
        }
    }

    // ---- head (head1+pn1 fused @512 blocks; pn2+pn3 fused @256 blocks) ----
    pn1_fused<<<BN / 8, 256, 0, stream>>>(stu_id, exer_id, kn_emb, statB, kdB,
                                          stu_bias, e_disc, pn1_w, pn1_b, h1);
    pn23_fused<<<BN / 16, 256, 0, stream>>>(h1, pn2_w, pn2_b, pn3_w, pn3_b, out);
    (void)out_size; (void)n_in; (void)in_sizes;
}

// Round 9
// 549.077 us; speedup vs baseline: 1.0900x; 1.0069x over previous
//
#include <hip/hip_runtime.h>
#include <hip/hip_bf16.h>

// Problem constants (from reference)
#define SN 50000
#define EN 20000
#define KN 128
#define DN 64
#define BN 4096
#define NE 1000000
#define NLAYER 3

// Column-chunk bucketing: chunk = 4096 gather-table rows (fp8: 0.5MB)
#define CH_SHIFT 12
#define NCH0 5                        // side0 (ui): cols index kdiff, EN -> 5 chunks
#define NCH1 13                       // side1 (iu): cols index stat,  SN -> 13 chunks
// fine bucket = (2*row + tagbit)*nch + chunk   (tagbit 0 = pos, 1 = neg)
#define SIDE1_BASE2 (2 * SN * NCH0)            // 500000
#define NTOT2 (2 * (SN * NCH0 + EN * NCH1))    // 1020000 fine buckets

// Two-pass partition sort
#define BIN_SHIFT 11
#define NBIN2 ((NTOT2 + 2047) >> 11)  // 499 coarse bins (2048 fine buckets each)
#define T1 4096                       // edges per part1 tile
#define PG1 ((NE + T1 - 1) / T1)      // 245 tiles per adjacency
#define HB 256                        // hist blocks per adjacency

typedef float f32x4 __attribute__((ext_vector_type(4)));
typedef float f32x2 __attribute__((ext_vector_type(2)));
typedef short bf16x8 __attribute__((ext_vector_type(8)));

__device__ __forceinline__ float sigmoidf_(float v) { return 1.f / (1.f + __expf(-v)); }
__device__ __forceinline__ float bf_lo(unsigned u) { return __uint_as_float(u << 16); }
__device__ __forceinline__ float bf_hi(unsigned u) { return __uint_as_float(u & 0xffff0000u); }
__device__ __forceinline__ float bf_one(unsigned short s) { return __uint_as_float((unsigned)s << 16); }
__device__ __forceinline__ unsigned packbf2(float a, float b) {
    __hip_bfloat16 ha = __float2bfloat16(a), hb = __float2bfloat16(b);
    unsigned short ua = *(unsigned short*)&ha, ub = *(unsigned short*)&hb;
    return (unsigned)ua | ((unsigned)ub << 16);
}
__device__ __forceinline__ unsigned short packbf1(float a) {
    __hip_bfloat16 ha = __float2bfloat16(a);
    return *(unsigned short*)&ha;
}
// fp8(e4m3) of a bf16 value — matches the old bf2fp8 two-step numerics
__device__ __forceinline__ unsigned char fp8_of_bf16(unsigned short h) {
    float f = bf_one(h);
    int pk = __builtin_amdgcn_cvt_pk_fp8_f32(f, f, 0, false);
    return (unsigned char)(pk & 0xff);
}
// stage 8 consecutive f32 -> 8 bf16 (uint4), same rounding as the old f2bf3z
__device__ __forceinline__ uint4 pack8bf(const float* src) {
    float4 a0 = *(const float4*)(src);
    float4 a1 = *(const float4*)(src + 4);
    uint4 pk;
    pk.x = packbf2(a0.x, a0.y); pk.y = packbf2(a0.z, a0.w);
    pk.z = packbf2(a1.x, a1.y); pk.w = packbf2(a1.z, a1.w);
    return pk;
}

struct CsrB {
    const int* rows[4]; const int* cols[4]; const float* vals[4];
};

__device__ __forceinline__ int bucket_idx(int a, int r, int cc) {
    int side = a >> 1;
    int nch = side ? NCH1 : NCH0;
    int base = side ? SIDE1_BASE2 : 0;
    int tb = a & 1;                    // a=0,2 pos (first); a=1,3 neg (second)
    return base + (2 * r + tb) * nch + (cc >> CH_SHIFT);
}

// ---------------------------------------------------------------------------
// MERGED: coarse histogram (blocks 0..4*HB-1) + projection MFMA GEMM
// (remaining blocks). Independent work; one dispatch slot saved.
// Projection stages the f32 kn_base with INLINE f32->bf16 conversion
// (bit-identical to the old f2bf3z table; removes that dispatch).
// ---------------------------------------------------------------------------
template <int KK>
__global__ __launch_bounds__(256) void hist_proj(
    CsrB c, int* __restrict__ cnt,
    const float* __restrict__ XS, const float* __restrict__ XE,
    const float* __restrict__ Wf,
    unsigned short* __restrict__ outS, unsigned char* __restrict__ f8S,
    unsigned short* __restrict__ outE, unsigned char* __restrict__ f8E,
    int nbS) {
    constexpr int PITCH = KK + 8;
    __shared__ int h[512];
    __shared__ unsigned short Wl[128 * PITCH];
    const int t = threadIdx.x;

    if ((int)blockIdx.x < 4 * HB) {
        // ---------------- histogram part ----------------
        h[t] = 0; h[t + 256] = 0;
        __syncthreads();
        const int a = blockIdx.x >> 8;
        const int tile = blockIdx.x & 255;
        const int per = (NE + HB - 1) / HB;
        const int beg = tile * per, end = min(beg + per, NE);
        for (int i = beg + t; i < end; i += 256)
            atomicAdd(&h[bucket_idx(a, c.rows[a][i], c.cols[a][i]) >> BIN_SHIFT], 1);
        __syncthreads();
        if (h[t]) atomicAdd(&cnt[t], h[t]);
        if (h[t + 256]) atomicAdd(&cnt[t + 256], h[t + 256]);
        return;
    }
    // ---------------- projection part ----------------
    const int bid = (int)blockIdx.x - 4 * HB;
    for (int idx = t * 8; idx < 128 * KK; idx += 2048) {
        int r = idx / KK, k = idx - r * KK;
        *(uint4*)(&Wl[r * PITCH + k]) = pack8bf(&Wf[idx]);
    }
    __syncthreads();
    const bool sideE = bid >= nbS;
    const float* X = sideE ? XE : XS;
    unsigned short* out = sideE ? outE : outS;
    unsigned char* f8 = sideE ? f8E : f8S;
    const int M = sideE ? EN : SN;
    const int lane = t & 63;
    const int nm = lane & 15;
    const int quad = lane >> 4;
    const int row0 = (bid - (sideE ? nbS : 0)) * 64 + (t >> 6) * 16;
    if (row0 >= M) return;

    f32x4 acc[8];
#pragma unroll
    for (int nt = 0; nt < 8; ++nt) acc[nt] = (f32x4){0.f, 0.f, 0.f, 0.f};

    const float* xrow = X + (size_t)(row0 + nm) * KK + quad * 8;
#pragma unroll
    for (int ks = 0; ks < KK / 32; ++ks) {
        float4 f0 = *(const float4*)(xrow + ks * 32);
        float4 f1 = *(const float4*)(xrow + ks * 32 + 4);
        unsigned q[4] = {packbf2(f0.x, f0.y), packbf2(f0.z, f0.w),
                         packbf2(f1.x, f1.y), packbf2(f1.z, f1.w)};
        bf16x8 a = *(bf16x8*)q;
#pragma unroll
        for (int nt = 0; nt < 8; ++nt) {
            bf16x8 b = *(const bf16x8*)(&Wl[(nt * 16 + nm) * PITCH + ks * 32 + quad * 8]);
            acc[nt] = __builtin_amdgcn_mfma_f32_16x16x32_bf16(a, b, acc[nt], 0, 0, 0);
        }
    }
    const size_t obase = (size_t)(row0 + quad * 4) * 128 + nm;
    unsigned short* orow = out + obase;
    unsigned char* frow = f8 + obase;
#pragma unroll
    for (int r = 0; r < 4; ++r)
#pragma unroll
        for (int nt = 0; nt < 8; ++nt) {
            unsigned short hh = packbf1(acc[nt][r]);
            orow[(size_t)r * 128 + nt * 16] = hh;
            frow[(size_t)r * 128 + nt * 16] = fp8_of_bf16(hh);
        }
}

// 1-block exclusive scan of coarse counts -> base[NBIN2+1] and tails[NBIN2]
__global__ __launch_bounds__(512) void scan_coarse(const int* __restrict__ cnt,
                                                   int* __restrict__ base,
                                                   int* __restrict__ tails) {
    __shared__ int sh[512];
    const int t = threadIdx.x;
    const int v = (t < NBIN2) ? cnt[t] : 0;
    sh[t] = v;
    __syncthreads();
    for (int o = 1; o < 512; o <<= 1) {
        int x = sh[t]; int u = (t >= o) ? sh[t - o] : 0;
        __syncthreads(); sh[t] = x + u; __syncthreads();
    }
    if (t < NBIN2) {
        const int ex = sh[t] - v;
        base[t] = ex;
        tails[t] = ex;
    }
    if (t == 511) base[NBIN2] = sh[511];
}

// ---------------------------------------------------------------------------
// part1: multisplit edges into coarse-bin segments with coalesced writes.
// Record int2: .x = col(0..15) | fine_bucket_low11(17..27), .y = f32 val (plain)
// ---------------------------------------------------------------------------
__global__ __launch_bounds__(512) void part1(CsrB c, int* __restrict__ tails,
                                             int2* __restrict__ stg) {
    __shared__ int2 srec[T1];
    __shared__ unsigned short sbin[T1];
    __shared__ int h[512], offs[512], gbase[512], sc[512];
    const int t = threadIdx.x;
    const int a = blockIdx.x / PG1;
    const int tile = blockIdx.x - a * PG1;
    const int beg = tile * T1;
    const int cnt = min(T1, NE - beg);
    h[t] = 0;
    __syncthreads();

    int2 rec[8]; int rbin[8]; int rrank[8];
#pragma unroll
    for (int k = 0; k < 8; ++k) {
        int o = t + k * 512;
        if (o < cnt) {
            int i = beg + o;
            int cc = c.cols[a][i];
            int B = bucket_idx(a, c.rows[a][i], cc);
            int bin = B >> BIN_SHIFT;
            rec[k] = make_int2(cc | ((B & 2047) << 17), __float_as_int(c.vals[a][i]));
            rbin[k] = bin;
            rrank[k] = atomicAdd(&h[bin], 1);
        } else {
            rbin[k] = -1;
        }
    }
    __syncthreads();
    sc[t] = h[t];
    __syncthreads();
    for (int o = 1; o < 512; o <<= 1) {
        int x = sc[t]; int u = (t >= o) ? sc[t - o] : 0;
        __syncthreads(); sc[t] = x + u; __syncthreads();
    }
    offs[t] = sc[t] - h[t];
    if (h[t] > 0) gbase[t] = atomicAdd(&tails[t], h[t]);
    __syncthreads();
#pragma unroll
    for (int k = 0; k < 8; ++k) {
        if (rbin[k] >= 0) {
            int pos = offs[rbin[k]] + rrank[k];
            srec[pos] = rec[k];
            sbin[pos] = (unsigned short)rbin[k];
        }
    }
    __syncthreads();
    for (int idx = t; idx < cnt; idx += 512) {
        int b = sbin[idx];
        stg[gbase[b] + (idx - offs[b])] = srec[idx];
    }
}

// ---------------------------------------------------------------------------
// part2: one block per coarse bin. Builds fine histogram+prefix in LDS
// (producing rp_all), then scatters into the bin's own ~128KB window.
// cv record: .x = bare column, .y = f32 value
// ---------------------------------------------------------------------------
__global__ __launch_bounds__(512) void part2(const int* __restrict__ coarseBase,
                                             const int2* __restrict__ stg,
                                             int* __restrict__ rp,
                                             int2* __restrict__ cv) {
    __shared__ int cnt2[2048];
    __shared__ int tsum[512];
    const int b = blockIdx.x;
    const int t = threadIdx.x;
    const int fineBase = b << BIN_SHIFT;
    const int nf = min(2048, NTOT2 - fineBase);
    const int segBeg = coarseBase[b];
    const int segEnd = coarseBase[b + 1];
    for (int i = t; i < 2048; i += 512) cnt2[i] = 0;
    __syncthreads();
    for (int e = segBeg + t; e < segEnd; e += 512)
        atomicAdd(&cnt2[((unsigned)stg[e].x) >> 17], 1);
    __syncthreads();
    const int i4 = t * 4;
    int v0 = cnt2[i4], v1 = cnt2[i4 + 1], v2 = cnt2[i4 + 2], v3 = cnt2[i4 + 3];
    tsum[t] = v0 + v1 + v2 + v3;
    __syncthreads();
    for (int o = 1; o < 512; o <<= 1) {
        int x = tsum[t]; int u = (t >= o) ? tsum[t - o] : 0;
        __syncthreads(); tsum[t] = x + u; __syncthreads();
    }
    const int pre = (t == 0) ? 0 : tsum[t - 1];
    const int p0 = pre, p1 = pre + v0, p2 = p1 + v1, p3 = p2 + v2;
    cnt2[i4] = p0; cnt2[i4 + 1] = p1; cnt2[i4 + 2] = p2; cnt2[i4 + 3] = p3;
    if (i4 + 0 < nf) rp[fineBase + i4 + 0] = segBeg + p0;
    if (i4 + 1 < nf) rp[fineBase + i4 + 1] = segBeg + p1;
    if (i4 + 2 < nf) rp[fineBase + i4 + 2] = segBeg + p2;
    if (i4 + 3 < nf) rp[fineBase + i4 + 3] = segBeg + p3;
    if (b == NBIN2 - 1 && t == 511) rp[NTOT2] = segEnd;
    __syncthreads();
    for (int e = segBeg + t; e < segEnd; e += 512) {
        int2 r = stg[e];
        int pos = segBeg + atomicAdd(&cnt2[((unsigned)r.x) >> 17], 1);
        cv[pos] = make_int2(r.x & 0xFFFF, r.y);
    }
}

// ---------------------------------------------------------------------------
// Fused dual-weight MFMA GEMM, BOTH sides in one dispatch (in-place safe):
//   out = (agg1 + d1.*y)@W1^T + (agg0 + d0.*y)@W0^T + (b1+b0)
// 512 threads / 128 rows per block. Stages the f32 weight tables with
// INLINE f32->bf16 conversion (bit-identical to the old pre-converted
// tables; the tables are L2-hot so the extra f32 reads are ~free).
// Full mode also writes the fp8 shadow inline. LIST mode (last layer):
// block processes 128 *list entries*; aggregation buffers compact
// [BN,128]; y,d gathered through ids; compact output (race-free under
// duplicate ids, bitwise-identical math).
// ---------------------------------------------------------------------------
template <bool LIST>
__global__ __launch_bounds__(512) void gemm2_mfma(
    const unsigned short* __restrict__ agg1S, const unsigned short* __restrict__ agg0S,
    const unsigned short* __restrict__ yS,
    const float* __restrict__ d1S, const float* __restrict__ d0S,
    unsigned short* __restrict__ outS, unsigned char* __restrict__ f8S,
    const unsigned short* __restrict__ agg1E, const unsigned short* __restrict__ agg0E,
    const unsigned short* __restrict__ yE,
    const float* __restrict__ d1E, const float* __restrict__ d0E,
    unsigned short* __restrict__ outE, unsigned char* __restrict__ f8E,
    const float* __restrict__ W1f, const float* __restrict__ W0f,
    const float* __restrict__ b1, const float* __restrict__ b0,
    const int* __restrict__ idsS, const int* __restrict__ idsE, int nblkS) {
    constexpr int PITCH = 136;
    __shared__ unsigned short Wl[2 * 128 * PITCH];
    const int t = threadIdx.x;
    for (int idx = t * 8; idx < 128 * 128; idx += 4096) {
        int r = idx >> 7, k = idx & 127;
        *(uint4*)(&Wl[r * PITCH + k]) = pack8bf(&W1f[idx]);
        *(uint4*)(&Wl[128 * PITCH + r * PITCH + k]) = pack8bf(&W0f[idx]);
    }
    __syncthreads();
    const bool sideE = (int)blockIdx.x >= nblkS;
    const unsigned short* agg1 = sideE ? agg1E : agg1S;
    const unsigned short* agg0 = sideE ? agg0E : agg0S;
    const unsigned short* y    = sideE ? yE : yS;
    const float* d1 = sideE ? d1E : d1S;
    const float* d0 = sideE ? d0E : d0S;
    unsigned short* out = sideE ? outE : outS;
    unsigned char* f8 = sideE ? f8E : f8S;
    const int M = LIST ? BN : (sideE ? EN : SN);
    const int lane = t & 63;
    const int nm = lane & 15;
    const int quad = lane >> 4;
    const int row0 = ((int)blockIdx.x - (sideE ? nblkS : 0)) * 128 + (t >> 6) * 16;
    if (row0 >= M) return;

    const int lrow = row0 + nm;                  // list index (LIST) or row
    int grow = lrow;                             // real row for y / d gathers
    if (LIST) grow = (sideE ? idsE : idsS)[lrow];

    const float d1v = d1[grow];
    const float d0v = d0[grow];

    f32x4 acc[8];
#pragma unroll
    for (int nt = 0; nt < 8; ++nt) acc[nt] = (f32x4){0.f, 0.f, 0.f, 0.f};

    const size_t rbA = (size_t)lrow * 128 + quad * 8;   // aggs: compact in LIST
    const size_t rbY = (size_t)grow * 128 + quad * 8;   // y: gathered in LIST
#pragma unroll
    for (int ks = 0; ks < 4; ++ks) {
        uint4 ua1 = *(const uint4*)(agg1 + rbA + ks * 32);
        uint4 ua0 = *(const uint4*)(agg0 + rbA + ks * 32);
        uint4 uy  = *(const uint4*)(y    + rbY + ks * 32);
        uint4 p1, p0;
        {
            unsigned* a1 = (unsigned*)&ua1; unsigned* a0 = (unsigned*)&ua0;
            unsigned* yy = (unsigned*)&uy;
            unsigned* q1 = (unsigned*)&p1; unsigned* q0 = (unsigned*)&p0;
#pragma unroll
            for (int w = 0; w < 4; ++w) {
                float ylo = bf_lo(yy[w]), yhi = bf_hi(yy[w]);
                q1[w] = packbf2(bf_lo(a1[w]) + d1v * ylo, bf_hi(a1[w]) + d1v * yhi);
                q0[w] = packbf2(bf_lo(a0[w]) + d0v * ylo, bf_hi(a0[w]) + d0v * yhi);
            }
        }
        bf16x8 af1 = *(bf16x8*)&p1;
        bf16x8 af0 = *(bf16x8*)&p0;
#pragma unroll
        for (int nt = 0; nt < 8; ++nt) {
            bf16x8 bw1 = *(const bf16x8*)(&Wl[(nt * 16 + nm) * PITCH + ks * 32 + quad * 8]);
            acc[nt] = __builtin_amdgcn_mfma_f32_16x16x32_bf16(af1, bw1, acc[nt], 0, 0, 0);
            bf16x8 bw0 = *(const bf16x8*)(&Wl[128 * PITCH + (nt * 16 + nm) * PITCH + ks * 32 + quad * 8]);
            acc[nt] = __builtin_amdgcn_mfma_f32_16x16x32_bf16(af0, bw0, acc[nt], 0, 0, 0);
        }
    }
    const size_t obase = (size_t)(row0 + quad * 4) * 128 + nm;
    unsigned short* orow = out + obase;
    unsigned char* frow = f8 + obase;
#pragma unroll
    for (int nt = 0; nt < 8; ++nt) {
        float bb = b1[nt * 16 + nm] + b0[nt * 16 + nm];
#pragma unroll
        for (int r = 0; r < 4; ++r) {
            unsigned short h = packbf1(acc[nt][r] + bb);
            orow[(size_t)r * 128 + nt * 16] = h;
            if (!LIST) frow[(size_t)r * 128 + nt * 16] = fp8_of_bf16(h);
        }
    }
}

// ---------------------------------------------------------------------------
// Quad-SPMM (round-1/3 form — empirical floor of all structural variants
// tried in rounds 2/4/5): 4 edges per wave instruction. Quarter-wave q
// handles edge e+q; lane c (0..15) covers cols 8c..8c+7 via one uint2 fp8
// gather + 4 cvt_pk_f32_fp8 + 4 packed-f32 FMAs. Tag phases serial (keeps
// one gather-table window live per wave; mixing thrashed per-XCD L2).
// Cross-quarter reduce via shfl_xor(16|32); quarter 0 writes the pos row,
// quarter 1 the neg row (16 lanes x 16B coalesced).
// LIST mode (last layer): only 2*BN waves; wave i handles row ids[i] and
// writes compact output row i (race-free under duplicate ids).
// ---------------------------------------------------------------------------
template <bool LIST>
__global__ __launch_bounds__(256) void spmm_all(
    const int* __restrict__ rp, const long long* __restrict__ cv,
    const unsigned char* __restrict__ kd8, const unsigned char* __restrict__ st8,
    unsigned short* __restrict__ as1, unsigned short* __restrict__ as0,
    unsigned short* __restrict__ ae1, unsigned short* __restrict__ ae0,
    const int* __restrict__ idsS, const int* __restrict__ idsE) {
    const int wave = (blockIdx.x * 256 + threadIdx.x) >> 6;
    const int lane = threadIdx.x & 63;
    const int NW = LIST ? 2 * BN : SN + EN;
    if (wave >= NW) return;
    const bool sideE = LIST ? (wave >= BN) : (wave >= SN);
    const int li = sideE ? (wave - (LIST ? BN : SN)) : wave;
    const int r = LIST ? (sideE ? idsE[li] : idsS[li]) : li;
    const int nch = sideE ? NCH1 : NCH0;
    const int* rpb = rp + (sideE ? SIDE1_BASE2 : 0);
    const int q = lane >> 4;           // quarter 0..3 -> edge e+q
    const int c = lane & 15;           // col group: cols 8c..8c+7
    const unsigned char* g8 = (sideE ? st8 : kd8) + c * 8;

    const int rbase = 2 * r * nch;
    const int e0 = rpb[rbase];
    const int em = rpb[rbase + nch];
    const int ee = rpb[rbase + 2 * nch];

    f32x2 accP[4], accN[4];
#pragma unroll
    for (int j = 0; j < 4; ++j) { accP[j] = (f32x2){0.f, 0.f}; accN[j] = (f32x2){0.f, 0.f}; }

#define QUAD(E, ACC)                                                        \
    {                                                                       \
        int col = (int)((E) & 0xFFFF);                                      \
        float v = __int_as_float((int)((E) >> 32));                         \
        f32x2 vv = {v, v};                                                  \
        uint2 u = *(const uint2*)(g8 + (col << 7));                         \
        ACC[0] += vv * __builtin_amdgcn_cvt_pk_f32_fp8((int)u.x, false);    \
        ACC[1] += vv * __builtin_amdgcn_cvt_pk_f32_fp8((int)u.x, true);     \
        ACC[2] += vv * __builtin_amdgcn_cvt_pk_f32_fp8((int)u.y, false);    \
        ACC[3] += vv * __builtin_amdgcn_cvt_pk_f32_fp8((int)u.y, true);     \
    }

    // phase 1: pos edges [e0, em)
    {
        int e = e0;
        for (; e + 16 <= em; e += 16) {
            long long E0 = cv[e + q];
            long long E1 = cv[e + 4 + q];
            long long E2 = cv[e + 8 + q];
            long long E3 = cv[e + 12 + q];
            QUAD(E0, accP) QUAD(E1, accP) QUAD(E2, accP) QUAD(E3, accP)
        }
        for (; e + 4 <= em; e += 4) {
            long long E0 = cv[e + q];
            QUAD(E0, accP)
        }
        if (e < em) {
            int idx = min(e + q, em - 1);
            long long E0 = cv[idx];
            if (e + q >= em) E0 &= 0xFFFFLL;   // keep col, zero value
            QUAD(E0, accP)
        }
    }
    // phase 2: neg edges [em, ee)
    {
        int e = em;
        for (; e + 16 <= ee; e += 16) {
            long long E0 = cv[e + q];
            long long E1 = cv[e + 4 + q];
            long long E2 = cv[e + 8 + q];
            long long E3 = cv[e + 12 + q];
            QUAD(E0, accN) QUAD(E1, accN) QUAD(E2, accN) QUAD(E3, accN)
        }
        for (; e + 4 <= ee; e += 4) {
            long long E0 = cv[e + q];
            QUAD(E0, accN)
        }
        if (e < ee) {
            int idx = min(e + q, ee - 1);
            long long E0 = cv[idx];
            if (e + q >= ee) E0 &= 0xFFFFLL;
            QUAD(E0, accN)
        }
    }
#undef QUAD

    // reduce over quarters (xor 16, then 32)
#pragma unroll
    for (int j = 0; j < 4; ++j) {
        accP[j].x += __shfl_xor(accP[j].x, 16);
        accP[j].y += __shfl_xor(accP[j].y, 16);
        accN[j].x += __shfl_xor(accN[j].x, 16);
        accN[j].y += __shfl_xor(accN[j].y, 16);
        accP[j].x += __shfl_xor(accP[j].x, 32);
        accP[j].y += __shfl_xor(accP[j].y, 32);
        accN[j].x += __shfl_xor(accN[j].x, 32);
        accN[j].y += __shfl_xor(accN[j].y, 32);
    }
    unsigned short* o1 = sideE ? ae1 : as1;
    unsigned short* o0 = sideE ? ae0 : as0;
    const int oi = LIST ? li : r;      // compact slot in LIST mode
    const int base = (oi << 7) + c * 8;
    if (q == 0) {
        uint4 w;
        w.x = packbf2(accP[0].x, accP[0].y);
        w.y = packbf2(accP[1].x, accP[1].y);
        w.z = packbf2(accP[2].x, accP[2].y);
        w.w = packbf2(accP[3].x, accP[3].y);
        *(uint4*)&o1[base] = w;
    } else if (q == 1) {
        uint4 w;
        w.x = packbf2(accN[0].x, accN[0].y);
        w.y = packbf2(accN[1].x, accN[1].y);
        w.z = packbf2(accN[2].x, accN[2].y);
        w.w = packbf2(accN[3].x, accN[3].y);
        *(uint4*)&o0[base] = w;
    }
}

// ---------------------------------------------------------------------------
// pn1 fused with head1 — ROWS=4 (1024 blocks; head is CU-coverage bound,
// round 7->8 confirmed: more blocks -> faster; weights are L2-hot so
// re-staging is ~free). x computed inline during staging;
// h1 = sig(x @ |pn1_w|^T + pn1_b). Ascending-k accumulation -> bitwise-id.
// ---------------------------------------------------------------------------
__global__ __launch_bounds__(256) void pn1_fused(
    const int* __restrict__ stu_id, const int* __restrict__ exer_id,
    const float* __restrict__ kn_emb, const unsigned short* __restrict__ statB,
    const unsigned short* __restrict__ kdB, const float* __restrict__ stu_bias,
    const float* __restrict__ e_disc,
    const float* __restrict__ W, const float* __restrict__ bias,
    float* __restrict__ out) {
    constexpr int KK = 128, NCOLS = 256, ROWS = 4, KP = 32;
    __shared__ float BT[KP * (NCOLS + 1)];
    __shared__ float Xl[ROWS * (KK + 1)];
    __shared__ float sdisc[ROWS], sbias[ROWS];
    const int t = threadIdx.x;
    const int row0 = blockIdx.x * ROWS;
    if (t < ROWS) {
        const int gr = row0 + t;
        sdisc[t] = sigmoidf_(e_disc[exer_id[gr]]);
        sbias[t] = stu_bias[stu_id[gr]];
    }
    __syncthreads();
    for (int idx = t; idx < ROWS * KK; idx += 256) {
        const int r = idx >> 7, k = idx & 127;
        const int gr = row0 + r;
        const float sb = sigmoidf_(bf_one(statB[(gr << 7) + k]) + sbias[r]);
        const float kd = sigmoidf_(bf_one(kdB[(gr << 7) + k]));
        Xl[r * (KK + 1) + k] = sdisc[r] * (sb - kd) * kn_emb[(gr << 7) + k];
    }
    const int j = t;                   // NCOLS == blockDim
    float acc[ROWS];
#pragma unroll
    for (int i = 0; i < ROWS; ++i) acc[i] = 0.f;

    for (int k0 = 0; k0 < KK; k0 += KP) {
        __syncthreads();
        for (int idx = t; idx < NCOLS * KP; idx += 256) {
            int jj = idx / KP, kp = idx % KP;
            BT[kp * (NCOLS + 1) + jj] = fabsf(W[jj * KK + k0 + kp]);
        }
        __syncthreads();
#pragma unroll
        for (int kp = 0; kp < KP; ++kp) {
            float b = BT[kp * (NCOLS + 1) + j];
#pragma unroll
            for (int rr = 0; rr < ROWS; ++rr)
                acc[rr] += Xl[rr * (KK + 1) + k0 + kp] * b;
        }
    }
    const float bj = bias[j];
#pragma unroll
    for (int rr = 0; rr < ROWS; ++rr)
        out[(row0 + rr) * NCOLS + j] = sigmoidf_(acc[rr] + bj);
}

// ---------------------------------------------------------------------------
// pn2 fused with pn3 — ROWS=8 (512 blocks). h2 kept in LDS;
// out = sig(h2.|pn3_w|+b3). Ascending-k accumulation -> bitwise-identical.
// ---------------------------------------------------------------------------
__global__ __launch_bounds__(256) void pn23_fused(
    const float* __restrict__ X, const float* __restrict__ W,
    const float* __restrict__ bias, const float* __restrict__ w3,
    const float* __restrict__ b3, float* __restrict__ out) {
    constexpr int KK = 256, NCOLS = 128, ROWS = 8, KP = 32;
    constexpr int RT = 4;              // NG = 2
    __shared__ float BT[KP * (NCOLS + 1)];
    __shared__ float Xl[ROWS * (KK + 1)];
    __shared__ float Sv[ROWS][NCOLS + 1];
    __shared__ float wl[128];
    const int t = threadIdx.x;
    const int j = t % NCOLS;
    const int rg = t / NCOLS;
    const int row0 = blockIdx.x * ROWS;
    if (t < 128) wl[t] = fabsf(w3[t]);

    for (int idx = t; idx < ROWS * KK; idx += 256) {
        const int r = idx >> 8, k = idx & 255;
        Xl[r * (KK + 1) + k] = X[(row0 + r) * KK + k];
    }
    float acc[RT];
#pragma unroll
    for (int i = 0; i < RT; ++i) acc[i] = 0.f;

    for (int k0 = 0; k0 < KK; k0 += KP) {
        __syncthreads();
        for (int idx = t; idx < NCOLS * KP; idx += 256) {
            int jj = idx / KP, kp = idx % KP;
            BT[kp * (NCOLS + 1) + jj] = fabsf(W[jj * KK + k0 + kp]);
        }
        __syncthreads();
#pragma unroll
        for (int kp = 0; kp < KP; ++kp) {
            float b = BT[kp * (NCOLS + 1) + j];
#pragma unroll
            for (int rr = 0; rr < RT; ++rr)
                acc[rr] += Xl[(rg * RT + rr) * (KK + 1) + k0 + kp] * b;
        }
    }
    const float bj = bias[j];
#pragma unroll
    for (int rr = 0; rr < RT; ++rr)
        Sv[rg * RT + rr][j] = sigmoidf_(acc[rr] + bj);
    __syncthreads();
    if (t < ROWS) {
        float a = 0.f;
#pragma unroll 4
        for (int k = 0; k < 128; ++k) a += Sv[t][k] * wl[k];
        out[row0 + t] = sigmoidf_(a + b3[0]);
    }
}

// ---------------------------------------------------------------------------
// Launch
// ---------------------------------------------------------------------------
static inline size_t align256(size_t x) { return (x + 255) & ~size_t(255); }

extern "C" void kernel_launch(void* const* d_in, const int* in_sizes, int n_in,
                              void* d_out, int out_size, void* d_ws, size_t ws_size,
                              hipStream_t stream) {
    const int*   stu_id   = (const int*)d_in[0];
    const int*   exer_id  = (const int*)d_in[1];
    const float* kn_emb   = (const float*)d_in[2];
    const float* stu_emb  = (const float*)d_in[3];
    const float* exer_emb = (const float*)d_in[4];
    const float* kn_base  = (const float*)d_in[5];
    const float* stu_bias = (const float*)d_in[6];
    const float* e_disc   = (const float*)d_in[7];
    const float* W1_w     = (const float*)d_in[8];
    const float* W1_b     = (const float*)d_in[9];
    const float* W0_w     = (const float*)d_in[10];
    const float* W0_b     = (const float*)d_in[11];
    const float* pn1_w    = (const float*)d_in[12];
    const float* pn1_b    = (const float*)d_in[13];
    const float* pn2_w    = (const float*)d_in[14];
    const float* pn2_b    = (const float*)d_in[15];
    const float* pn3_w    = (const float*)d_in[16];
    const float* pn3_b    = (const float*)d_in[17];
    const int*   ui1_r = (const int*)d_in[18]; const int* ui1_c = (const int*)d_in[19];
    const float* ui1_v = (const float*)d_in[20];
    const int*   iu1_r = (const int*)d_in[21]; const int* iu1_c = (const int*)d_in[22];
    const float* iu1_v = (const float*)d_in[23];
    const int*   ui0_r = (const int*)d_in[24]; const int* ui0_c = (const int*)d_in[25];
    const float* ui0_v = (const float*)d_in[26];
    const int*   iu0_r = (const int*)d_in[27]; const int* iu0_c = (const int*)d_in[28];
    const float* iu0_v = (const float*)d_in[29];
    const float* d_i_1 = (const float*)d_in[30];
    const float* d_j_1 = (const float*)d_in[31];
    const float* d_i_0 = (const float*)d_in[32];
    const float* d_j_0 = (const float*)d_in[33];
    float* out = (float*)d_out;

    typedef unsigned short u16;
    typedef unsigned char u8;
    char* p = (char*)d_ws;
    size_t off = 0;
    auto alloc = [&](size_t bytes) { char* q = p + off; off += align256(bytes); return q; };
    // bf16 state
    u16* stat  = (u16*)alloc(size_t(SN) * KN * 2);
    u16* kdiff = (u16*)alloc(size_t(EN) * KN * 2);
    // fp8 shadows
    u8* st8 = (u8*)alloc(size_t(SN) * KN);
    u8* kd8 = (u8*)alloc(size_t(EN) * KN);
    // aggregation buffers
    u16* as1 = (u16*)alloc(size_t(SN) * KN * 2);
    u16* as0 = (u16*)alloc(size_t(SN) * KN * 2);
    u16* ae1 = (u16*)alloc(size_t(EN) * KN * 2);
    u16* ae0 = (u16*)alloc(size_t(EN) * KN * 2);
    // compact last-layer outputs [BN,128] bf16
    u16* statB = (u16*)alloc(size_t(BN) * KN * 2);
    u16* kdB   = (u16*)alloc(size_t(BN) * KN * 2);
    // sort structures
    int*  coarseCnt  = (int*)alloc(512 * 4);
    int*  coarseBase = (int*)alloc((NBIN2 + 1) * 4);
    int*  tails      = (int*)alloc(512 * 4);
    int*  rp_all     = (int*)alloc(size_t(NTOT2 + 1) * 4);
    int2* stg        = (int2*)alloc(size_t(4) * NE * 8);
    int2* cv_all     = (int2*)alloc(size_t(4) * NE * 8);
    // head intermediate
    float* h1 = (float*)alloc(size_t(BN) * 256 * 4);
    if (off > ws_size) return;

    CsrB c;
    c.rows[0] = ui1_r; c.cols[0] = ui1_c; c.vals[0] = ui1_v;
    c.rows[1] = ui0_r; c.cols[1] = ui0_c; c.vals[1] = ui0_v;
    c.rows[2] = iu1_r; c.cols[2] = iu1_c; c.vals[2] = iu1_v;
    c.rows[3] = iu0_r; c.cols[3] = iu0_c; c.vals[3] = iu0_v;

    // ---- zero coarse counters (DMA; replaces the f2bf3z kernel slot) ----
    hipMemsetAsync(coarseCnt, 0, 512 * 4, stream);

    // ---- merged: coarse histogram + projections (independent work) ----
    const int nbS = (SN + 63) / 64, nbE = (EN + 63) / 64;
    hist_proj<DN><<<4 * HB + nbS + nbE, 256, 0, stream>>>(
        c, coarseCnt, stu_emb, exer_emb, kn_base, stat, st8, kdiff, kd8, nbS);

    // ---- rest of the two-pass partition sort ----
    scan_coarse<<<1, 512, 0, stream>>>(coarseCnt, coarseBase, tails);
    part1<<<4 * PG1, 512, 0, stream>>>(c, tails, stg);
    part2<<<NBIN2, 512, 0, stream>>>(coarseBase, stg, rp_all, cv_all);

    const int nblkS = (SN + 127) / 128, nblkE = (EN + 127) / 128;

    // ---- GCN layers (layers 0,1 full; layer 2 only at gathered rows) ----
    for (int l = 0; l < NLAYER; ++l) {
        if (l < NLAYER - 1) {
            spmm_all<false><<<(SN + EN + 3) / 4, 256, 0, stream>>>(
                rp_all, (const long long*)cv_all, kd8, st8, as1, as0, ae1, ae0,
                nullptr, nullptr);
            gemm2_mfma<false><<<nblkS + nblkE, 512, 0, stream>>>(
                as1, as0, stat, d_i_1, d_i_0, stat, st8,
                ae1, ae0, kdiff, d_j_1, d_j_0, kdiff, kd8,
                W1_w, W0_w, W1_b, W0_b, nullptr, nullptr, nblkS);
        } else {
            // last layer: only rows referenced by the head (compact outputs)
            spmm_all<true><<<(2 * BN) / 4, 256, 0, stream>>>(
                rp_all, (const long long*)cv_all, kd8, st8, as1, as0, ae1, ae0,
                stu_id, exer_id);
            gemm2_mfma<true><<<2 * (BN / 128), 512, 0, stream>>>(
                as1, as0, stat, d_i_1, d_i_0, statB, nullptr,
                ae1, ae0, kdiff, d_j_1, d_j_0, kdB, nullptr,
                W1_w, W0_w, W1_b, W0_b, stu_id, exer_id, BN / 128);
        }
    }

    // ---- head (head1+pn1 fused @1024 blocks; pn2+pn3 fused @512 blocks) ----
    pn1_fused<<<BN / 4, 256, 0, stream>>>(stu_id, exer_id, kn_emb, statB, kdB,
                                          stu_bias, e_disc, pn1_w, pn1_b, h1);
    pn23_fused<<<BN / 8, 256, 0, stream>>>(h1, pn2_w, pn2_b, pn3_w, pn3_b, out);
    (void)out_size; (void)n_in; (void)in_sizes;
}